// Round 6
// baseline (215.445 us; speedup 1.0000x reference)
//
#include <hip/hip_runtime.h>
#include <stdint.h>

#define S_LEN 2048
#define EMB   1024
#define NH    16
#define HD    64
#define BK 64

typedef __bf16 bf16x8 __attribute__((ext_vector_type(8)));
typedef short  short4v __attribute__((ext_vector_type(4)));
typedef unsigned int uint2v __attribute__((ext_vector_type(2)));
typedef unsigned int uint4v __attribute__((ext_vector_type(4)));
typedef float  floatx4 __attribute__((ext_vector_type(4)));
typedef _Float16 half4v __attribute__((ext_vector_type(4)));
typedef _Float16 half8v __attribute__((ext_vector_type(8)));

// Guards need compilable fallbacks: the HIP host pass reports no amdgcn builtins.
#if defined(__has_builtin)
#if __has_builtin(__builtin_amdgcn_mfma_f32_16x16x16bf16_1k)
#define HAVE_MFMA16 1
#endif
#if __has_builtin(__builtin_amdgcn_exp2f)
#define EXP2F __builtin_amdgcn_exp2f   // single v_exp_f32 (quarter-rate) — NOT ocml exp2f
#endif
#endif
#ifndef EXP2F
#define EXP2F exp2f
#endif

// 0.125 (1/sqrt(64)) * log2(e): Q pre-scale so softmax runs in exp2 domain
#define QSCALE 0.1803368801111204f

__device__ __forceinline__ unsigned short f2bf(float f) {
  unsigned u = __builtin_bit_cast(unsigned, f);
  u += 0x7fffu + ((u >> 16) & 1u);   // RNE
  return (unsigned short)(u >> 16);
}
__device__ __forceinline__ unsigned short f2bf_hu(float f) {
  return (unsigned short)((__builtin_bit_cast(unsigned, f) + 0x8000u) >> 16);
}
// pack 2 floats -> [bf16(b):bf16(a)] via v_perm, half-up
__device__ __forceinline__ unsigned packbf2(float a, float b) {
  unsigned ua = __builtin_bit_cast(unsigned, a) + 0x8000u;
  unsigned ub = __builtin_bit_cast(unsigned, b) + 0x8000u;
  return __builtin_amdgcn_perm(ub, ua, 0x07060302);
}

__global__ __launch_bounds__(256) void cvt_all(const float* __restrict__ x,
                                               const float* __restrict__ Wq,
                                               const float* __restrict__ Wk,
                                               const float* __restrict__ Wv,
                                               const float* __restrict__ Wo,
                                               unsigned short* __restrict__ xb,
                                               unsigned short* __restrict__ Wqb,
                                               unsigned short* __restrict__ Wkb,
                                               unsigned short* __restrict__ Wvb,
                                               unsigned short* __restrict__ Wob) {
  int blk = blockIdx.x;
  const float* s; unsigned short* d; int off;
  if (blk < 4096)      { s = x;  d = xb;  off = blk; }
  else if (blk < 5120) { s = Wq; d = Wqb; off = blk - 4096; }
  else if (blk < 6144) { s = Wk; d = Wkb; off = blk - 5120; }
  else if (blk < 7168) { s = Wv; d = Wvb; off = blk - 6144; }
  else                 { s = Wo; d = Wob; off = blk - 7168; }
  int i = (off * 256 + threadIdx.x) * 4;
  float4 v = *(const float4*)(s + i);
  ushort4 o;
  o.x = f2bf(v.x); o.y = f2bf(v.y); o.z = f2bf(v.z); o.w = f2bf(v.w);
  *(ushort4*)(d + i) = o;
}

__device__ __forceinline__ void stage16(const void* g, void* l) {
  __builtin_amdgcn_global_load_lds(
      (const __attribute__((address_space(1))) void*)g,
      (__attribute__((address_space(3))) void*)l, 16, 0, 0);
}

// QKV projection v2: 128x128 tile (m97 geometry: 4 waves x 64x64, acc[4][4]).
// Operand-swapped MFMA (C' = W x^T). Grid (32,8,3) = 768 blocks = 3/CU.
// mode 1: bf16 [B,H,S,D] (8B packed stores); mode 2: bf16 [B,H,D,S] (coalesced along s)
__global__ __launch_bounds__(256, 3) void qkv_gemm(const unsigned short* __restrict__ xb,
                                                   const unsigned short* __restrict__ Wqb,
                                                   const unsigned short* __restrict__ Wkb,
                                                   const unsigned short* __restrict__ Wvb,
                                                   const float* __restrict__ bq,
                                                   const float* __restrict__ bk,
                                                   const float* __restrict__ bv,
                                                   unsigned short* __restrict__ Qb,
                                                   unsigned short* __restrict__ Kb,
                                                   unsigned short* __restrict__ Vtb) {
  __shared__ unsigned short As[128 * BK];
  __shared__ unsigned short Bs[128 * BK];
  const int z = blockIdx.z;
  const unsigned short* Bm = (z == 0) ? Wqb : (z == 1) ? Wkb : Wvb;
  const float* bias        = (z == 0) ? bq  : (z == 1) ? bk  : bv;
  unsigned short* outp     = (z == 0) ? Qb  : (z == 1) ? Kb  : Vtb;
  const float scale = (z == 0) ? QSCALE : 1.0f;
  const int mode = (z == 2) ? 2 : 1;

  const int tid  = threadIdx.x;
  const int lane = tid & 63;
  const int wave = tid >> 6;
  const int m16  = lane & 15;
  const int quad = lane >> 4;
  const int m0 = blockIdx.x * 128;
  const int n0 = blockIdx.y * 128;
  const int wrow = (wave >> 1) * 64;
  const int wcol = (wave & 1) * 64;
  const int K = 1024;

  floatx4 acc[4][4];
  for (int i = 0; i < 4; ++i)
    for (int j = 0; j < 4; ++j) acc[i][j] = floatx4{0.f, 0.f, 0.f, 0.f};

  for (int k0 = 0; k0 < K; k0 += BK) {
    __syncthreads();
    for (int i = 0; i < 4; ++i) {
      int c = i * 256 + tid;
      int row = c >> 3, col = (c & 7) << 3;
      stage16(xb + (size_t)(m0 + row) * K + k0 + col,
              (char*)As + (size_t)(i * 256 + wave * 64) * 16);
      stage16(Bm + (size_t)(n0 + row) * K + k0 + col,
              (char*)Bs + (size_t)(i * 256 + wave * 64) * 16);
    }
    __syncthreads();
    for (int kk = 0; kk < 2; ++kk) {
      bf16x8 af[4], bfr[4];
      for (int ti = 0; ti < 4; ++ti)
        af[ti] = *(const bf16x8*)(As + (wrow + ti * 16 + m16) * BK + kk * 32 + quad * 8);
      for (int tj = 0; tj < 4; ++tj)
        bfr[tj] = *(const bf16x8*)(Bs + (wcol + tj * 16 + m16) * BK + kk * 32 + quad * 8);
      for (int ti = 0; ti < 4; ++ti)
        for (int tj = 0; tj < 4; ++tj)
          acc[ti][tj] = __builtin_amdgcn_mfma_f32_16x16x32_bf16(bfr[tj], af[ti], acc[ti][tj], 0, 0, 0);
    }
  }

  if (mode == 1) {
    for (int ti = 0; ti < 4; ++ti) {
      int m = m0 + wrow + ti * 16 + m16;
      int b = m >> 11, ss = m & 2047;
      for (int tj = 0; tj < 4; ++tj) {
        int n = n0 + wcol + tj * 16 + quad * 4;
        int hh = n >> 6, d = n & 63;
        float4 b4 = *(const float4*)(bias + n);
        float v0 = (acc[ti][tj][0] + b4.x) * scale;
        float v1 = (acc[ti][tj][1] + b4.y) * scale;
        float v2 = (acc[ti][tj][2] + b4.z) * scale;
        float v3 = (acc[ti][tj][3] + b4.w) * scale;
        uint2v pk{packbf2(v0, v1), packbf2(v2, v3)};
        *(uint2v*)((unsigned short*)outp +
                   ((size_t)(b * NH + hh) * S_LEN + ss) * HD + d) = pk;
      }
    }
  } else {
    for (int tj = 0; tj < 4; ++tj)
      for (int reg = 0; reg < 4; ++reg) {
        int n = n0 + wcol + tj * 16 + quad * 4 + reg;
        int hh = n >> 6, d = n & 63;
        float bv = bias[n];
        for (int ti = 0; ti < 4; ++ti) {
          int m = m0 + wrow + ti * 16 + m16;
          int b = m >> 11, ss = m & 2047;
          ((unsigned short*)outp)[((size_t)(b * NH + hh) * HD + d) * S_LEN + ss] =
              f2bf_hu(acc[ti][tj][reg] + bv);
        }
      }
  }
}

// Output projection v4: 128x64 tile, 4 waves x 64x32 (acc[4][2]), with the
// KV-split MERGE fused into A-staging. BK=64=HD so each k0 iteration covers
// EXACTLY ONE HEAD (h = k0>>6): per-row-per-head 1/(l1+l2) comes from an
// 8 KB LDS table rLs[128][16] built in the prologue (R5 bug: l is per-HEAD,
// a single per-row scalar mixed heads). A-merge is reg-staged (load 2x f16x8,
// add, scale, pack bf16, ds_write); B-panel via async DMA. Grid (32,16).
__global__ __launch_bounds__(256, 4) void out_gemm(const _Float16* __restrict__ Oph,  // [2 split][B*S][EMB] f16
                                                   const float* __restrict__ Lp,      // [2 split][B*S][NH] f32
                                                   const unsigned short* __restrict__ Wob,
                                                   const float* __restrict__ bo,
                                                   float* __restrict__ out) {
  __shared__ unsigned short As[128 * BK];
  __shared__ unsigned short Bs[64 * BK];
  __shared__ float rLs[128 * 16];   // [row][head] = 1/(l1+l2)
  const int tid  = threadIdx.x;
  const int lane = tid & 63;
  const int wave = tid >> 6;
  const int m16  = lane & 15;
  const int quad = lane >> 4;
  const int m0 = blockIdx.x * 128;
  const int n0 = blockIdx.y * 64;
  const int wrow = (wave >> 1) * 64;
  const int wcol = (wave & 1) * 32;
  const int K = 1024, N = 1024;

  // prologue: 2048 (row, head) entries / 256 thr = 8 each
  for (int e = 0; e < 8; ++e) {
    int idx = tid * 8 + e;           // row = idx>>4, h = idx&15
    int m = m0 + (idx >> 4);
    rLs[idx] = 1.f / (Lp[(size_t)m * 16 + (idx & 15)] +
                      Lp[(size_t)65536 + (size_t)m * 16 + (idx & 15)]);
  }

  floatx4 acc[4][2];
  for (int i = 0; i < 4; ++i)
    for (int j = 0; j < 2; ++j) acc[i][j] = floatx4{0.f, 0.f, 0.f, 0.f};

  for (int k0 = 0; k0 < K; k0 += BK) {
    __syncthreads();   // also publishes rLs before first use
    const int hh = k0 >> 6;
    for (int i = 0; i < 2; ++i) {   // B-panel: async DMA first (overlaps A math)
      int c = i * 256 + tid;
      int row = c >> 3, col = (c & 7) << 3;
      stage16(Wob + (size_t)(n0 + row) * K + k0 + col,
              (char*)Bs + (size_t)(i * 256 + wave * 64) * 16);
    }
    for (int i = 0; i < 4; ++i) {   // A-panel: load f16 partials, merge, pack
      int c = i * 256 + tid;
      int row = c >> 3, col = (c & 7) << 3;
      int m = m0 + row;
      half8v x1 = *(const half8v*)(Oph + (size_t)m * EMB + k0 + col);
      half8v x2 = *(const half8v*)(Oph + (size_t)(4096 + m) * EMB + k0 + col);
      float r = rLs[row * 16 + hh];
      unsigned u0 = packbf2(((float)x1[0] + (float)x2[0]) * r, ((float)x1[1] + (float)x2[1]) * r);
      unsigned u1 = packbf2(((float)x1[2] + (float)x2[2]) * r, ((float)x1[3] + (float)x2[3]) * r);
      unsigned u2 = packbf2(((float)x1[4] + (float)x2[4]) * r, ((float)x1[5] + (float)x2[5]) * r);
      unsigned u3 = packbf2(((float)x1[6] + (float)x2[6]) * r, ((float)x1[7] + (float)x2[7]) * r);
      *(uint4v*)((char*)As + (size_t)c * 16) = uint4v{u0, u1, u2, u3};
    }
    __syncthreads();
    for (int kk = 0; kk < 2; ++kk) {
      bf16x8 af[4], bfr[2];
      for (int ti = 0; ti < 4; ++ti)
        af[ti] = *(const bf16x8*)(As + (wrow + ti * 16 + m16) * BK + kk * 32 + quad * 8);
      for (int tj = 0; tj < 2; ++tj)
        bfr[tj] = *(const bf16x8*)(Bs + (wcol + tj * 16 + m16) * BK + kk * 32 + quad * 8);
      for (int ti = 0; ti < 4; ++ti)
        for (int tj = 0; tj < 2; ++tj)
          acc[ti][tj] = __builtin_amdgcn_mfma_f32_16x16x32_bf16(af[ti], bfr[tj], acc[ti][tj], 0, 0, 0);
    }
  }

  for (int tj = 0; tj < 2; ++tj) {
    int n = n0 + wcol + tj * 16 + m16;
    float bv = bo[n];
    for (int ti = 0; ti < 4; ++ti)
      for (int reg = 0; reg < 4; ++reg) {
        int m = m0 + wrow + ti * 16 + quad * 4 + reg;
        out[(size_t)m * N + n] = acc[ti][tj][reg] + bv;
      }
  }
}

// Flash attention v10b: KV-SPLIT x2. Grid (32 bh, 16 qt, 2 split) = 1024
// blocks -> 4 blocks/CU (LDS 33 KB) -> 4 waves/SIMD. R4 showed 2 waves/SIMD
// leaves ~27% issue-idle and the 512-block grid capped occupancy; splitting
// KV doubles resident waves at ZERO reuse loss (per-CU MFMA/LDS-read/staging
// totals unchanged). Fixed-reference softmax (p=exp2(s), no max) makes the
// merge exact: O = (O1+O2)/(l1+l2), fused into out_gemm. Partials f16.
// l is PER (b,h,s): Lp layout [split][B*S][NH] (R5 bug: heads raced on one slot).
__global__ __launch_bounds__(256, 4) void attn_kernel(const unsigned short* __restrict__ Qb,  // [B,H,S,D] *QSCALE
                                                      const unsigned short* __restrict__ Kb,  // [B,H,S,D]
                                                      const unsigned short* __restrict__ Vtb, // [B,H,D,S]
                                                      const int* __restrict__ mask,           // [B,S]
                                                      _Float16* __restrict__ Oph,             // [2][B*S][EMB]
                                                      float* __restrict__ Lp) {               // [2][B*S][NH]
  __shared__ unsigned short Ks[2 * 64 * 64];   // [p][kv][d], chunk' = chunk ^ (kv&7), 8 chunks/row
  __shared__ unsigned short Vts[2 * 64 * 64];  // [p][d][kv], chunk' = chunk ^ (d&7), 8 chunks/row
  __shared__ int zw[4];
#ifndef HAVE_MFMA16
  __shared__ unsigned short Pq[4 * 16 * 72];
#endif

  const int tid  = threadIdx.x;
  const int lane = tid & 63;
  const int wave = tid >> 6;          // 0..3
  const int m16  = lane & 15;
  const int quad = lane >> 4;
  const int bh = blockIdx.x;          // fastest -> XCD = bh % 8 (K/V L2-resident per XCD)
  const int qt = blockIdx.y;
  const int split = blockIdx.z;       // 0: kv [0,1024), 1: kv [1024,2048)
  const int b  = bh >> 4;
  const int hh = bh & 15;
  const int q0 = qt * 128;
  const size_t head = (size_t)bh * S_LEN * HD;
  const int kvbase = split * 1024;

  // 2 Q-fragments per wave: rows q0 + wave*32 + qs*16 + m16
  bf16x8 qf[2][2];
  for (int qs = 0; qs < 2; ++qs) {
    const unsigned short* qrow = Qb + head + (size_t)(q0 + wave * 32 + qs * 16 + m16) * HD;
    qf[qs][0] = *(const bf16x8*)(qrow + quad * 8);
    qf[qs][1] = *(const bf16x8*)(qrow + 32 + quad * 8);
  }

  // DMA source addresses (LDS dest linear; XOR swizzle folded into the global
  // per-lane address). Wave w owns rows [w*16, w*16+16) of each 64-row tile.
  // Per stage16 j: row = w*16 + j*8 + (lane>>3), chunkpos = lane&7,
  // global chunk = chunkpos ^ (row&7) = (lane&7) ^ (lane>>3).
  const int kr = lane >> 3, kc = lane & 7;
  const unsigned short* kg0 = Kb + head + (size_t)(kvbase + wave * 16 + kr) * HD + ((kc ^ kr) << 3);
  const unsigned short* vg0 = Vtb + head + (size_t)(wave * 16 + kr) * S_LEN + kvbase + ((kc ^ kr) << 3);
  const int* mrow = mask + b * S_LEN;

#define STAGE_KV(pp, kb_)                                                      \
  {                                                                            \
    const unsigned short* ksrc = kg0 + (size_t)(kb_) * 64 * HD;                \
    char* kdst = (char*)Ks + (pp) * 8192 + wave * 2048;                        \
    stage16(ksrc,           kdst);                                             \
    stage16(ksrc + 8 * HD,  kdst + 1024);                                      \
    const unsigned short* vsrc = vg0 + (kb_) * 64;                             \
    char* vdst = (char*)Vts + (pp) * 8192 + wave * 2048;                       \
    stage16(vsrc,              vdst);                                          \
    stage16(vsrc + 8 * S_LEN,  vdst + 1024);                                   \
  }

  float l_run[2] = {0.f, 0.f};   // per-lane partial; cross-lane reduce deferred
  floatx4 acc_o[2][4];
  for (int qs = 0; qs < 2; ++qs)
    for (int ti = 0; ti < 4; ++ti) acc_o[qs][ti] = floatx4{0.f, 0.f, 0.f, 0.f};

  // one-time block-wide mask scan over THIS split's half (1024 ints / 256 thr)
  {
    int4 a = *(const int4*)(mrow + kvbase + tid * 4);
    bool z = (a.x & a.y & a.z & a.w) == 0;  // mask values are 0/1
    unsigned long long bal = __ballot(z);
    if (lane == 0) zw[wave] = (bal != 0ull) ? 1 : 0;
  }

  STAGE_KV(0, 0);
  __syncthreads();   // drains vmcnt(0): tile 0 resident; zw visible
  const bool anymask = (zw[0] | zw[1] | zw[2] | zw[3]) != 0;

  const int xs = m16 & 7;
  const floatx4 fz = floatx4{0.f, 0.f, 0.f, 0.f};

  for (int kb = 0; kb < 16; ++kb) {
    const int p = kb & 1;
    const unsigned short* Kp = Ks + p * 4096;
    const unsigned short* Vp = Vts + p * 4096;
    if (kb < 15) STAGE_KV(p ^ 1, kb + 1);   // async into the other buffer

    // S^T[kv][q]: A = K fragment (m=kv), B = Q fragment (n=q). Each K frag
    // feeds both q-sets.
    floatx4 acc_s[2][4];
    {
      bf16x8 kf[4];
      for (int tj = 0; tj < 4; ++tj)
        kf[tj] = *(const bf16x8*)&Kp[(tj * 16 + m16) * 64 + ((quad ^ xs) << 3)];
      for (int tj = 0; tj < 4; ++tj) {
        acc_s[0][tj] = __builtin_amdgcn_mfma_f32_16x16x32_bf16(kf[tj], qf[0][0], fz, 0, 0, 0);
        acc_s[1][tj] = __builtin_amdgcn_mfma_f32_16x16x32_bf16(kf[tj], qf[1][0], fz, 0, 0, 0);
      }
      for (int tj = 0; tj < 4; ++tj)
        kf[tj] = *(const bf16x8*)&Kp[(tj * 16 + m16) * 64 + (((4 + quad) ^ xs) << 3)];
      for (int tj = 0; tj < 4; ++tj) {
        acc_s[0][tj] = __builtin_amdgcn_mfma_f32_16x16x32_bf16(kf[tj], qf[0][1], acc_s[0][tj], 0, 0, 0);
        acc_s[1][tj] = __builtin_amdgcn_mfma_f32_16x16x32_bf16(kf[tj], qf[1][1], acc_s[1][tj], 0, 0, 0);
      }
    }

    unsigned up[2][8];
    for (int qs = 0; qs < 2; ++qs) {
      if (anymask) {
        for (int t = 0; t < 4; ++t)
          for (int r = 0; r < 4; ++r) {
            int idx = kvbase + kb * 64 + t * 16 + quad * 4 + r;
            acc_s[qs][t][r] += (mrow[idx] == 0) ? -1e9f : 0.f;
          }
      }
      float sl = 0.f;
      for (int i = 0; i < 8; ++i) {
        float p0 = EXP2F(acc_s[qs][i >> 1][(i & 1) * 2]);
        float p1 = EXP2F(acc_s[qs][i >> 1][(i & 1) * 2 + 1]);
        sl += p0 + p1;
        up[qs][i] = packbf2(p0, p1);
      }
      l_run[qs] += sl;   // per-lane partial (covers this lane's kv subset)
    }

#ifdef HAVE_MFMA16
    for (int ti = 0; ti < 4; ++ti)
      for (int c = 0; c < 4; ++c) {
        short4v vf = *(const short4v*)&Vp[(ti * 16 + m16) * 64 +
                                          (((2 * c + (quad >> 1)) ^ xs) << 3) +
                                          ((quad & 1) << 2)];
        short4v Pb0 = __builtin_bit_cast(short4v, uint2v{up[0][2 * c], up[0][2 * c + 1]});
        short4v Pb1 = __builtin_bit_cast(short4v, uint2v{up[1][2 * c], up[1][2 * c + 1]});
        acc_o[0][ti] = __builtin_amdgcn_mfma_f32_16x16x16bf16_1k(vf, Pb0, acc_o[0][ti], 0, 0, 0);
        acc_o[1][ti] = __builtin_amdgcn_mfma_f32_16x16x16bf16_1k(vf, Pb1, acc_o[1][ti], 0, 0, 0);
      }
#else
    // host-parse / non-gfx950 fallback: per-wave LDS round-trip + x32
    {
      unsigned short* Pw = Pq + wave * 16 * 72;
      for (int qs = 0; qs < 2; ++qs) {
        for (int t = 0; t < 4; ++t) {
          *(unsigned*)&Pw[m16 * 72 + t * 16 + quad * 4]     = up[qs][2 * t];
          *(unsigned*)&Pw[m16 * 72 + t * 16 + quad * 4 + 2] = up[qs][2 * t + 1];
        }
        for (int kk = 0; kk < 2; ++kk) {
          bf16x8 pf = *(const bf16x8*)&Pw[m16 * 72 + kk * 32 + quad * 8];
          for (int ti = 0; ti < 4; ++ti) {
            bf16x8 vfb = *(const bf16x8*)&Vp[(ti * 16 + m16) * 64 +
                                             (((kk * 4 + quad) ^ xs) << 3)];
            acc_o[qs][ti] = __builtin_amdgcn_mfma_f32_16x16x32_bf16(vfb, pf, acc_o[qs][ti], 0, 0, 0);
          }
        }
      }
    }
#endif

    __syncthreads();   // readers of buf p done; DMA for p^1 drained (vmcnt 0)
  }

  for (int qs = 0; qs < 2; ++qs) {
    // deferred cross-lane reduce: q-row sum lives on lanes m16, +16, +32, +48
    l_run[qs] += __shfl_xor(l_run[qs], 16);
    l_run[qs] += __shfl_xor(l_run[qs], 32);
    int orow = q0 + wave * 32 + qs * 16 + m16;
    size_t mrow_g = (size_t)(split * 4096 + b * 2048 + orow);   // [split][B*S] row
    if (quad == 0) Lp[mrow_g * 16 + hh] = l_run[qs];            // per-HEAD slot
    for (int ti = 0; ti < 4; ++ti) {
      half4v ho;
      ho[0] = (_Float16)acc_o[qs][ti][0];
      ho[1] = (_Float16)acc_o[qs][ti][1];
      ho[2] = (_Float16)acc_o[qs][ti][2];
      ho[3] = (_Float16)acc_o[qs][ti][3];
      int e = hh * HD + ti * 16 + quad * 4;
      *(half4v*)&Oph[mrow_g * EMB + e] = ho;
    }
  }
#undef STAGE_KV
}

extern "C" void kernel_launch(void* const* d_in, const int* in_sizes, int n_in,
                              void* d_out, int out_size, void* d_ws, size_t ws_size,
                              hipStream_t stream) {
  const float* x  = (const float*)d_in[0];
  const int* mask = (const int*)d_in[1];
  const float* Wq = (const float*)d_in[2];
  const float* bq = (const float*)d_in[3];
  const float* Wk = (const float*)d_in[4];
  const float* bk = (const float*)d_in[5];
  const float* Wv = (const float*)d_in[6];
  const float* bv = (const float*)d_in[7];
  const float* Wo = (const float*)d_in[8];
  const float* bo = (const float*)d_in[9];
  float* out = (float*)d_out;

  char* ws = (char*)d_ws;
  unsigned short* xb  = (unsigned short*)(ws);               // 8 MB
  unsigned short* Wqb = (unsigned short*)(ws + 8388608);     // 2 MB
  unsigned short* Wkb = (unsigned short*)(ws + 10485760);    // 2 MB
  unsigned short* Wvb = (unsigned short*)(ws + 12582912);    // 2 MB
  unsigned short* Wob = (unsigned short*)(ws + 14680064);    // 2 MB
  unsigned short* Qb  = (unsigned short*)(ws + 16777216);    // 8 MB [B,H,S,D]
  unsigned short* Kbb = (unsigned short*)(ws + 25165824);    // 8 MB [B,H,S,D]
  unsigned short* Vtb = (unsigned short*)(ws + 33554432);    // 8 MB [B,H,D,S]
  _Float16* Oph       = (_Float16*)(ws + 41943040);          // 16 MB [2][B*S][EMB] f16
  float* Lp           = (float*)(ws + 58720256);             // 512 KB [2][B*S][NH] f32 (end ~56.6 MB)

  cvt_all<<<dim3(8192), dim3(256), 0, stream>>>(x, Wq, Wk, Wv, Wo, xb, Wqb, Wkb, Wvb, Wob);
  qkv_gemm<<<dim3(32, 8, 3), dim3(256), 0, stream>>>(xb, Wqb, Wkb, Wvb, bq, bk, bv, Qb, Kbb, Vtb);
  attn_kernel<<<dim3(32, 16, 2), dim3(256), 0, stream>>>(Qb, Kbb, Vtb, mask, Oph, Lp);
  out_gemm<<<dim3(32, 16), dim3(256), 0, stream>>>(Oph, Lp, Wob, bo, out);
}

// Round 9
// 200.756 us; speedup vs baseline: 1.0732x; 1.0732x over previous
//
#include <hip/hip_runtime.h>
#include <stdint.h>

#define S_LEN 2048
#define EMB   1024
#define NH    16
#define HD    64
#define BK 64

typedef __bf16 bf16x8 __attribute__((ext_vector_type(8)));
typedef short  short4v __attribute__((ext_vector_type(4)));
typedef unsigned int uint2v __attribute__((ext_vector_type(2)));
typedef float  floatx4 __attribute__((ext_vector_type(4)));

// Guards need compilable fallbacks: the HIP host pass reports no amdgcn builtins.
#if defined(__has_builtin)
#if __has_builtin(__builtin_amdgcn_mfma_f32_16x16x16bf16_1k)
#define HAVE_MFMA16 1
#endif
#if __has_builtin(__builtin_amdgcn_exp2f)
#define EXP2F __builtin_amdgcn_exp2f   // single v_exp_f32 (quarter-rate) — NOT ocml exp2f
#endif
#endif
#ifndef EXP2F
#define EXP2F exp2f
#endif

// 0.125 (1/sqrt(64)) * log2(e): Q pre-scale so softmax runs in exp2 domain
#define QSCALE 0.1803368801111204f

__device__ __forceinline__ unsigned short f2bf(float f) {
  unsigned u = __builtin_bit_cast(unsigned, f);
  u += 0x7fffu + ((u >> 16) & 1u);   // RNE
  return (unsigned short)(u >> 16);
}
__device__ __forceinline__ unsigned short f2bf_hu(float f) {
  return (unsigned short)((__builtin_bit_cast(unsigned, f) + 0x8000u) >> 16);
}
// pack 2 floats -> [bf16(b):bf16(a)] via v_perm, half-up.
// NOTE (R7 post-mortem): v_cvt_pk_bf16_f32 inline-asm variant FAILED correctness
// (absmax 1.56e-2 ~ pair-swap error signature) — operand->half mapping unverified.
// Keep the proven v_perm path.
__device__ __forceinline__ unsigned packbf2(float a, float b) {
  unsigned ua = __builtin_bit_cast(unsigned, a) + 0x8000u;
  unsigned ub = __builtin_bit_cast(unsigned, b) + 0x8000u;
  return __builtin_amdgcn_perm(ub, ua, 0x07060302);
}

__global__ __launch_bounds__(256) void cvt_all(const float* __restrict__ x,
                                               const float* __restrict__ Wq,
                                               const float* __restrict__ Wk,
                                               const float* __restrict__ Wv,
                                               const float* __restrict__ Wo,
                                               unsigned short* __restrict__ xb,
                                               unsigned short* __restrict__ Wqb,
                                               unsigned short* __restrict__ Wkb,
                                               unsigned short* __restrict__ Wvb,
                                               unsigned short* __restrict__ Wob) {
  int blk = blockIdx.x;
  const float* s; unsigned short* d; int off;
  if (blk < 4096)      { s = x;  d = xb;  off = blk; }
  else if (blk < 5120) { s = Wq; d = Wqb; off = blk - 4096; }
  else if (blk < 6144) { s = Wk; d = Wkb; off = blk - 5120; }
  else if (blk < 7168) { s = Wv; d = Wvb; off = blk - 6144; }
  else                 { s = Wo; d = Wob; off = blk - 7168; }
  int i = (off * 256 + threadIdx.x) * 4;
  float4 v = *(const float4*)(s + i);
  ushort4 o;
  o.x = f2bf(v.x); o.y = f2bf(v.y); o.z = f2bf(v.z); o.w = f2bf(v.w);
  *(ushort4*)(d + i) = o;
}

__device__ __forceinline__ void stage16(const void* g, void* l) {
  __builtin_amdgcn_global_load_lds(
      (const __attribute__((address_space(1))) void*)g,
      (__attribute__((address_space(3))) void*)l, 16, 0, 0);
}

// QKV projection v3: 128x128 tile (4 waves x 64x64, acc[4][4]) + XCD-stripe
// L2 swizzle. Without it, A-panels are re-read by all 24 (n,z) pairs and
// B-panels by all 32 m-blocks (~384 MB of panel traffic; per-XCD working set
// ~7MB > 4MB L2 -> HBM-bound). Remap (XCD = lid%8, measured m09): each XCD
// owns a contiguous 4-m-block A-stripe (1MB), iterates n fastest, z slowest:
// working set = A-stripe + one z's B panels ~3MB < 4MB L2.
// mode 1: bf16 [B,H,S,D] (8B packed stores); mode 2: bf16 [B,H,D,S]
__global__ __launch_bounds__(256, 3) void qkv_gemm(const unsigned short* __restrict__ xb,
                                                   const unsigned short* __restrict__ Wqb,
                                                   const unsigned short* __restrict__ Wkb,
                                                   const unsigned short* __restrict__ Wvb,
                                                   const float* __restrict__ bq,
                                                   const float* __restrict__ bk,
                                                   const float* __restrict__ bv,
                                                   unsigned short* __restrict__ Qb,
                                                   unsigned short* __restrict__ Kb,
                                                   unsigned short* __restrict__ Vtb) {
  __shared__ unsigned short As[128 * BK];
  __shared__ unsigned short Bs[128 * BK];

  const int lid = blockIdx.x + 32 * blockIdx.y + 256 * blockIdx.z;
  const int xcd = lid & 7;
  const int seq = lid >> 3;           // 0..95 per XCD
  const int z   = seq >> 5;           // 0..2 (slowest: B set changes per z)
  const int ml  = (seq & 31) >> 3;    // 0..3 (A-stripe member)
  const int nb  = seq & 7;            // 0..7 (fastest: cycles B panels)
  const int m0 = (xcd * 4 + ml) * 128;
  const int n0 = nb * 128;

  const unsigned short* Bm = (z == 0) ? Wqb : (z == 1) ? Wkb : Wvb;
  const float* bias        = (z == 0) ? bq  : (z == 1) ? bk  : bv;
  unsigned short* outp     = (z == 0) ? Qb  : (z == 1) ? Kb  : Vtb;
  const float scale = (z == 0) ? QSCALE : 1.0f;
  const int mode = (z == 2) ? 2 : 1;

  const int tid  = threadIdx.x;
  const int lane = tid & 63;
  const int wave = tid >> 6;
  const int m16  = lane & 15;
  const int quad = lane >> 4;
  const int wrow = (wave >> 1) * 64;
  const int wcol = (wave & 1) * 64;
  const int K = 1024;

  floatx4 acc[4][4];
  for (int i = 0; i < 4; ++i)
    for (int j = 0; j < 4; ++j) acc[i][j] = floatx4{0.f, 0.f, 0.f, 0.f};

  for (int k0 = 0; k0 < K; k0 += BK) {
    __syncthreads();
    for (int i = 0; i < 4; ++i) {
      int c = i * 256 + tid;
      int row = c >> 3, col = (c & 7) << 3;
      stage16(xb + (size_t)(m0 + row) * K + k0 + col,
              (char*)As + (size_t)(i * 256 + wave * 64) * 16);
      stage16(Bm + (size_t)(n0 + row) * K + k0 + col,
              (char*)Bs + (size_t)(i * 256 + wave * 64) * 16);
    }
    __syncthreads();
    for (int kk = 0; kk < 2; ++kk) {
      bf16x8 af[4], bfr[4];
      for (int ti = 0; ti < 4; ++ti)
        af[ti] = *(const bf16x8*)(As + (wrow + ti * 16 + m16) * BK + kk * 32 + quad * 8);
      for (int tj = 0; tj < 4; ++tj)
        bfr[tj] = *(const bf16x8*)(Bs + (wcol + tj * 16 + m16) * BK + kk * 32 + quad * 8);
      for (int ti = 0; ti < 4; ++ti)
        for (int tj = 0; tj < 4; ++tj)
          acc[ti][tj] = __builtin_amdgcn_mfma_f32_16x16x32_bf16(bfr[tj], af[ti], acc[ti][tj], 0, 0, 0);
    }
  }

  if (mode == 1) {
    for (int ti = 0; ti < 4; ++ti) {
      int m = m0 + wrow + ti * 16 + m16;
      int b = m >> 11, ss = m & 2047;
      for (int tj = 0; tj < 4; ++tj) {
        int n = n0 + wcol + tj * 16 + quad * 4;
        int hh = n >> 6, d = n & 63;
        float4 b4 = *(const float4*)(bias + n);
        float v0 = (acc[ti][tj][0] + b4.x) * scale;
        float v1 = (acc[ti][tj][1] + b4.y) * scale;
        float v2 = (acc[ti][tj][2] + b4.z) * scale;
        float v3 = (acc[ti][tj][3] + b4.w) * scale;
        uint2v pk{packbf2(v0, v1), packbf2(v2, v3)};
        *(uint2v*)((unsigned short*)outp +
                   ((size_t)(b * NH + hh) * S_LEN + ss) * HD + d) = pk;
      }
    }
  } else {
    for (int tj = 0; tj < 4; ++tj)
      for (int reg = 0; reg < 4; ++reg) {
        int n = n0 + wcol + tj * 16 + quad * 4 + reg;
        int hh = n >> 6, d = n & 63;
        float bv = bias[n];
        for (int ti = 0; ti < 4; ++ti) {
          int m = m0 + wrow + ti * 16 + m16;
          int b = m >> 11, ss = m & 2047;
          ((unsigned short*)outp)[((size_t)(b * NH + hh) * HD + d) * S_LEN + ss] =
              f2bf_hu(acc[ti][tj][reg] + bv);
        }
      }
  }
}

// Output projection v5: 128x64 tile, 4 waves x 64x32 (acc[4][2]), DMA-staged
// both panels, plus the same XCD-stripe swizzle: each XCD owns a 4-m A-stripe
// (1MB) and cycles all 16 B panels (2MB) -> working set 3MB < 4MB L2
// (was A 128MB + B 64MB refetch).
__global__ __launch_bounds__(256, 4) void out_gemm(const unsigned short* __restrict__ Ab,
                                                   const unsigned short* __restrict__ Wob,
                                                   const float* __restrict__ bo,
                                                   float* __restrict__ out) {
  __shared__ unsigned short As[128 * BK];
  __shared__ unsigned short Bs[64 * BK];
  const int lid = blockIdx.x + 32 * blockIdx.y;
  const int xcd = lid & 7;
  const int seq = lid >> 3;           // 0..63 per XCD
  const int m0 = (xcd * 4 + (seq >> 4)) * 128;
  const int n0 = (seq & 15) * 64;     // fastest: cycles B panels

  const int tid  = threadIdx.x;
  const int lane = tid & 63;
  const int wave = tid >> 6;
  const int m16  = lane & 15;
  const int quad = lane >> 4;
  const int wrow = (wave >> 1) * 64;
  const int wcol = (wave & 1) * 32;
  const int K = 1024, N = 1024;

  floatx4 acc[4][2];
  for (int i = 0; i < 4; ++i)
    for (int j = 0; j < 2; ++j) acc[i][j] = floatx4{0.f, 0.f, 0.f, 0.f};

  for (int k0 = 0; k0 < K; k0 += BK) {
    __syncthreads();
    for (int i = 0; i < 4; ++i) {
      int c = i * 256 + tid;
      int row = c >> 3, col = (c & 7) << 3;
      stage16(Ab + (size_t)(m0 + row) * K + k0 + col,
              (char*)As + (size_t)(i * 256 + wave * 64) * 16);
    }
    for (int i = 0; i < 2; ++i) {
      int c = i * 256 + tid;
      int row = c >> 3, col = (c & 7) << 3;
      stage16(Wob + (size_t)(n0 + row) * K + k0 + col,
              (char*)Bs + (size_t)(i * 256 + wave * 64) * 16);
    }
    __syncthreads();
    for (int kk = 0; kk < 2; ++kk) {
      bf16x8 af[4], bfr[2];
      for (int ti = 0; ti < 4; ++ti)
        af[ti] = *(const bf16x8*)(As + (wrow + ti * 16 + m16) * BK + kk * 32 + quad * 8);
      for (int tj = 0; tj < 2; ++tj)
        bfr[tj] = *(const bf16x8*)(Bs + (wcol + tj * 16 + m16) * BK + kk * 32 + quad * 8);
      for (int ti = 0; ti < 4; ++ti)
        for (int tj = 0; tj < 2; ++tj)
          acc[ti][tj] = __builtin_amdgcn_mfma_f32_16x16x32_bf16(af[ti], bfr[tj], acc[ti][tj], 0, 0, 0);
    }
  }

  for (int tj = 0; tj < 2; ++tj) {
    int n = n0 + wcol + tj * 16 + m16;
    float bv = bo[n];
    for (int ti = 0; ti < 4; ++ti)
      for (int reg = 0; reg < 4; ++reg) {
        int m = m0 + wrow + ti * 16 + quad * 4 + reg;
        out[(size_t)m * N + n] = acc[ti][tj][reg] + bv;
      }
  }
}

// Flash attention v9 (R4's passing version, byte-identical softmax path):
// KVBLK=64, 4 waves, 32 q-rows/wave (2 Q-frags/wave: every K/V LDS fragment
// feeds two MFMAs). Staging: global_load_lds DMA, pre-swizzled global source,
// LDS dest linear; double buffer, one barrier/tile. FIXED-REFERENCE softmax:
// p = exp2(s) directly, O = sum(pV)/sum(p); l-reduce deferred to epilogue.
__global__ __launch_bounds__(256, 4) void attn_kernel(const unsigned short* __restrict__ Qb,  // [B,H,S,D] *QSCALE
                                                      const unsigned short* __restrict__ Kb,  // [B,H,S,D]
                                                      const unsigned short* __restrict__ Vtb, // [B,H,D,S]
                                                      const int* __restrict__ mask,           // [B,S]
                                                      unsigned short* __restrict__ attnb) {   // [B,S,E]
  __shared__ unsigned short Ks[2 * 64 * 64];   // [p][kv][d], chunk' = chunk ^ (kv&7), 8 chunks/row
  __shared__ unsigned short Vts[2 * 64 * 64];  // [p][d][kv], chunk' = chunk ^ (d&7), 8 chunks/row
  __shared__ int zw[4];
#ifndef HAVE_MFMA16
  __shared__ unsigned short Pq[4 * 16 * 72];
#endif

  const int tid  = threadIdx.x;
  const int lane = tid & 63;
  const int wave = tid >> 6;          // 0..3
  const int m16  = lane & 15;
  const int quad = lane >> 4;
  const int bh = blockIdx.x;          // fastest -> XCD = bh % 8 (K/V L2-resident per XCD)
  const int qt = blockIdx.y;
  const int b  = bh >> 4;
  const int h  = bh & 15;
  const int q0 = qt * 128;
  const size_t head = (size_t)bh * S_LEN * HD;

  // 2 Q-fragments per wave: rows q0 + wave*32 + qs*16 + m16
  bf16x8 qf[2][2];
  for (int qs = 0; qs < 2; ++qs) {
    const unsigned short* qrow = Qb + head + (size_t)(q0 + wave * 32 + qs * 16 + m16) * HD;
    qf[qs][0] = *(const bf16x8*)(qrow + quad * 8);
    qf[qs][1] = *(const bf16x8*)(qrow + 32 + quad * 8);
  }

  // DMA source addresses (LDS dest linear; XOR swizzle folded into the global
  // per-lane address). Wave w owns rows [w*16, w*16+16) of each 64-row tile.
  // Per stage16 j: row = w*16 + j*8 + (lane>>3), chunkpos = lane&7,
  // global chunk = chunkpos ^ (row&7) = (lane&7) ^ (lane>>3).
  const int kr = lane >> 3, kc = lane & 7;
  const unsigned short* kg0 = Kb + head + (size_t)(wave * 16 + kr) * HD + ((kc ^ kr) << 3);
  const unsigned short* vg0 = Vtb + head + (size_t)(wave * 16 + kr) * S_LEN + ((kc ^ kr) << 3);
  const int* mrow = mask + b * S_LEN;

#define STAGE_KV(pp, kb_)                                                      \
  {                                                                            \
    const unsigned short* ksrc = kg0 + (size_t)(kb_) * 64 * HD;                \
    char* kdst = (char*)Ks + (pp) * 8192 + wave * 2048;                        \
    stage16(ksrc,           kdst);                                             \
    stage16(ksrc + 8 * HD,  kdst + 1024);                                      \
    const unsigned short* vsrc = vg0 + (kb_) * 64;                             \
    char* vdst = (char*)Vts + (pp) * 8192 + wave * 2048;                       \
    stage16(vsrc,              vdst);                                          \
    stage16(vsrc + 8 * S_LEN,  vdst + 1024);                                   \
  }

  float l_run[2] = {0.f, 0.f};   // per-lane partial; cross-lane reduce deferred
  floatx4 acc_o[2][4];
  for (int qs = 0; qs < 2; ++qs)
    for (int ti = 0; ti < 4; ++ti) acc_o[qs][ti] = floatx4{0.f, 0.f, 0.f, 0.f};

  // one-time block-wide mask scan (2048 ints / 256 thr = 2 int4 each)
  {
    const int4* mp = (const int4*)(mrow + tid * 8);
    int4 a = mp[0], c4 = mp[1];
    bool z = (a.x & a.y & a.z & a.w & c4.x & c4.y & c4.z & c4.w) == 0;  // mask values are 0/1
    unsigned long long bal = __ballot(z);
    if (lane == 0) zw[wave] = (bal != 0ull) ? 1 : 0;
  }

  STAGE_KV(0, 0);
  __syncthreads();   // drains vmcnt(0): tile 0 resident; zw visible
  const bool anymask = (zw[0] | zw[1] | zw[2] | zw[3]) != 0;

  const int xs = m16 & 7;
  const floatx4 fz = floatx4{0.f, 0.f, 0.f, 0.f};

  for (int kb = 0; kb < 32; ++kb) {
    const int p = kb & 1;
    const unsigned short* Kp = Ks + p * 4096;
    const unsigned short* Vp = Vts + p * 4096;
    if (kb < 31) STAGE_KV(p ^ 1, kb + 1);   // async into the other buffer

    // S^T[kv][q]: A = K fragment (m=kv), B = Q fragment (n=q). Each K frag
    // feeds both q-sets.
    floatx4 acc_s[2][4];
    {
      bf16x8 kf[4];
      for (int tj = 0; tj < 4; ++tj)
        kf[tj] = *(const bf16x8*)&Kp[(tj * 16 + m16) * 64 + ((quad ^ xs) << 3)];
      for (int tj = 0; tj < 4; ++tj) {
        acc_s[0][tj] = __builtin_amdgcn_mfma_f32_16x16x32_bf16(kf[tj], qf[0][0], fz, 0, 0, 0);
        acc_s[1][tj] = __builtin_amdgcn_mfma_f32_16x16x32_bf16(kf[tj], qf[1][0], fz, 0, 0, 0);
      }
      for (int tj = 0; tj < 4; ++tj)
        kf[tj] = *(const bf16x8*)&Kp[(tj * 16 + m16) * 64 + (((4 + quad) ^ xs) << 3)];
      for (int tj = 0; tj < 4; ++tj) {
        acc_s[0][tj] = __builtin_amdgcn_mfma_f32_16x16x32_bf16(kf[tj], qf[0][1], acc_s[0][tj], 0, 0, 0);
        acc_s[1][tj] = __builtin_amdgcn_mfma_f32_16x16x32_bf16(kf[tj], qf[1][1], acc_s[1][tj], 0, 0, 0);
      }
    }

    unsigned up[2][8];
    for (int qs = 0; qs < 2; ++qs) {
      if (anymask) {
        for (int t = 0; t < 4; ++t)
          for (int r = 0; r < 4; ++r) {
            int idx = kb * 64 + t * 16 + quad * 4 + r;
            acc_s[qs][t][r] += (mrow[idx] == 0) ? -1e9f : 0.f;
          }
      }
      float sl = 0.f;
      for (int i = 0; i < 8; ++i) {
        float p0 = EXP2F(acc_s[qs][i >> 1][(i & 1) * 2]);
        float p1 = EXP2F(acc_s[qs][i >> 1][(i & 1) * 2 + 1]);
        sl += p0 + p1;
        up[qs][i] = packbf2(p0, p1);
      }
      l_run[qs] += sl;   // per-lane partial (covers this lane's kv subset)
    }

#ifdef HAVE_MFMA16
    for (int ti = 0; ti < 4; ++ti)
      for (int c = 0; c < 4; ++c) {
        short4v vf = *(const short4v*)&Vp[(ti * 16 + m16) * 64 +
                                          (((2 * c + (quad >> 1)) ^ xs) << 3) +
                                          ((quad & 1) << 2)];
        short4v Pb0 = __builtin_bit_cast(short4v, uint2v{up[0][2 * c], up[0][2 * c + 1]});
        short4v Pb1 = __builtin_bit_cast(short4v, uint2v{up[1][2 * c], up[1][2 * c + 1]});
        acc_o[0][ti] = __builtin_amdgcn_mfma_f32_16x16x16bf16_1k(vf, Pb0, acc_o[0][ti], 0, 0, 0);
        acc_o[1][ti] = __builtin_amdgcn_mfma_f32_16x16x16bf16_1k(vf, Pb1, acc_o[1][ti], 0, 0, 0);
      }
#else
    // host-parse / non-gfx950 fallback: per-wave LDS round-trip + x32
    {
      unsigned short* Pw = Pq + wave * 16 * 72;
      for (int qs = 0; qs < 2; ++qs) {
        for (int t = 0; t < 4; ++t) {
          *(unsigned*)&Pw[m16 * 72 + t * 16 + quad * 4]     = up[qs][2 * t];
          *(unsigned*)&Pw[m16 * 72 + t * 16 + quad * 4 + 2] = up[qs][2 * t + 1];
        }
        for (int kk = 0; kk < 2; ++kk) {
          bf16x8 pf = *(const bf16x8*)&Pw[m16 * 72 + kk * 32 + quad * 8];
          for (int ti = 0; ti < 4; ++ti) {
            bf16x8 vfb = *(const bf16x8*)&Vp[(ti * 16 + m16) * 64 +
                                             (((kk * 4 + quad) ^ xs) << 3)];
            acc_o[qs][ti] = __builtin_amdgcn_mfma_f32_16x16x32_bf16(vfb, pf, acc_o[qs][ti], 0, 0, 0);
          }
        }
      }
    }
#endif

    __syncthreads();   // readers of buf p done; DMA for p^1 drained (vmcnt 0)
  }

  for (int qs = 0; qs < 2; ++qs) {
    // deferred cross-lane reduce: q-row sum lives on lanes m16, +16, +32, +48
    l_run[qs] += __shfl_xor(l_run[qs], 16);
    l_run[qs] += __shfl_xor(l_run[qs], 32);
    float rl = 1.f / l_run[qs];
    int orow = q0 + wave * 32 + qs * 16 + m16;
    for (int ti = 0; ti < 4; ++ti) {
      ushort4 o;
      o.x = f2bf_hu(acc_o[qs][ti][0] * rl);
      o.y = f2bf_hu(acc_o[qs][ti][1] * rl);
      o.z = f2bf_hu(acc_o[qs][ti][2] * rl);
      o.w = f2bf_hu(acc_o[qs][ti][3] * rl);
      int e = h * HD + ti * 16 + quad * 4;
      *(ushort4*)&attnb[((size_t)(b * S_LEN + orow)) * EMB + e] = o;
    }
  }
#undef STAGE_KV
}

extern "C" void kernel_launch(void* const* d_in, const int* in_sizes, int n_in,
                              void* d_out, int out_size, void* d_ws, size_t ws_size,
                              hipStream_t stream) {
  const float* x  = (const float*)d_in[0];
  const int* mask = (const int*)d_in[1];
  const float* Wq = (const float*)d_in[2];
  const float* bq = (const float*)d_in[3];
  const float* Wk = (const float*)d_in[4];
  const float* bk = (const float*)d_in[5];
  const float* Wv = (const float*)d_in[6];
  const float* bv = (const float*)d_in[7];
  const float* Wo = (const float*)d_in[8];
  const float* bo = (const float*)d_in[9];
  float* out = (float*)d_out;

  char* ws = (char*)d_ws;
  unsigned short* xb  = (unsigned short*)(ws);               // 8 MB
  unsigned short* Wqb = (unsigned short*)(ws + 8388608);     // 2 MB
  unsigned short* Wkb = (unsigned short*)(ws + 10485760);    // 2 MB
  unsigned short* Wvb = (unsigned short*)(ws + 12582912);    // 2 MB
  unsigned short* Wob = (unsigned short*)(ws + 14680064);    // 2 MB
  unsigned short* Qb  = (unsigned short*)(ws + 16777216);    // 8 MB [B,H,S,D]
  unsigned short* Kbb = (unsigned short*)(ws + 25165824);    // 8 MB [B,H,S,D]
  unsigned short* Vtb = (unsigned short*)(ws + 33554432);    // 8 MB [B,H,D,S]
  unsigned short* Ab  = (unsigned short*)(ws + 41943040);    // 8 MB [B,S,E]

  cvt_all<<<dim3(8192), dim3(256), 0, stream>>>(x, Wq, Wk, Wv, Wo, xb, Wqb, Wkb, Wvb, Wob);
  qkv_gemm<<<dim3(32, 8, 3), dim3(256), 0, stream>>>(xb, Wqb, Wkb, Wvb, bq, bk, bv, Qb, Kbb, Vtb);
  attn_kernel<<<dim3(32, 16), dim3(256), 0, stream>>>(Qb, Kbb, Vtb, mask, Ab);
  out_gemm<<<dim3(32, 16), dim3(256), 0, stream>>>(Ab, Wob, bo, out);
}

// Round 10
// 200.069 us; speedup vs baseline: 1.0769x; 1.0034x over previous
//
#include <hip/hip_runtime.h>
#include <stdint.h>

#define S_LEN 2048
#define EMB   1024
#define NH    16
#define HD    64
#define BK 64

typedef __bf16 bf16x8 __attribute__((ext_vector_type(8)));
typedef short  short4v __attribute__((ext_vector_type(4)));
typedef unsigned int uint2v __attribute__((ext_vector_type(2)));
typedef unsigned int uint4v __attribute__((ext_vector_type(4)));
typedef float  floatx4 __attribute__((ext_vector_type(4)));

// Guards need compilable fallbacks: the HIP host pass reports no amdgcn builtins.
#if defined(__has_builtin)
#if __has_builtin(__builtin_amdgcn_mfma_f32_16x16x16bf16_1k)
#define HAVE_MFMA16 1
#endif
#if __has_builtin(__builtin_amdgcn_exp2f)
#define EXP2F __builtin_amdgcn_exp2f   // single v_exp_f32 (quarter-rate) — NOT ocml exp2f
#endif
#endif
#ifndef EXP2F
#define EXP2F exp2f
#endif

// 0.125 (1/sqrt(64)) * log2(e): Q pre-scale so softmax runs in exp2 domain
#define QSCALE 0.1803368801111204f

__device__ __forceinline__ unsigned short f2bf(float f) {
  unsigned u = __builtin_bit_cast(unsigned, f);
  u += 0x7fffu + ((u >> 16) & 1u);   // RNE
  return (unsigned short)(u >> 16);
}
__device__ __forceinline__ unsigned short f2bf_hu(float f) {
  return (unsigned short)((__builtin_bit_cast(unsigned, f) + 0x8000u) >> 16);
}
// pack 2 floats -> [bf16(b):bf16(a)] via v_perm, half-up.
// NOTE (R7): v_cvt_pk_bf16_f32 inline-asm FAILED correctness — keep v_perm path.
__device__ __forceinline__ unsigned packbf2(float a, float b) {
  unsigned ua = __builtin_bit_cast(unsigned, a) + 0x8000u;
  unsigned ub = __builtin_bit_cast(unsigned, b) + 0x8000u;
  return __builtin_amdgcn_perm(ub, ua, 0x07060302);
}

__global__ __launch_bounds__(256) void cvt_all(const float* __restrict__ x,
                                               const float* __restrict__ Wq,
                                               const float* __restrict__ Wk,
                                               const float* __restrict__ Wv,
                                               const float* __restrict__ Wo,
                                               unsigned short* __restrict__ xb,
                                               unsigned short* __restrict__ Wqb,
                                               unsigned short* __restrict__ Wkb,
                                               unsigned short* __restrict__ Wvb,
                                               unsigned short* __restrict__ Wob) {
  int blk = blockIdx.x;
  const float* s; unsigned short* d; int off;
  if (blk < 4096)      { s = x;  d = xb;  off = blk; }
  else if (blk < 5120) { s = Wq; d = Wqb; off = blk - 4096; }
  else if (blk < 6144) { s = Wk; d = Wkb; off = blk - 5120; }
  else if (blk < 7168) { s = Wv; d = Wvb; off = blk - 6144; }
  else                 { s = Wo; d = Wob; off = blk - 7168; }
  int i = (off * 256 + threadIdx.x) * 4;
  float4 v = *(const float4*)(s + i);
  ushort4 o;
  o.x = f2bf(v.x); o.y = f2bf(v.y); o.z = f2bf(v.z); o.w = f2bf(v.w);
  *(ushort4*)(d + i) = o;
}

__device__ __forceinline__ void stage16(const void* g, void* l) {
  __builtin_amdgcn_global_load_lds(
      (const __attribute__((address_space(1))) void*)g,
      (__attribute__((address_space(3))) void*)l, 16, 0, 0);
}

// QKV projection v4: 128x128 tile (4 waves x 64x64, acc[4][4]) + XCD-stripe
// swizzle (kept from R9, proven correct) + LDS-STAGED COALESCED EPILOGUE.
// R9 analysis: all tensors are LLC-resident, so qkv isn't traffic-bound —
// but its stores were pathological: mode 1 stored 8B per lane at 128B stride
// (64 cache lines touched per wave-store, 16x L2 write amplification over
// 16 MB); mode 2 stored 64 scalar 2B per thread. Fix: after the K-loop the
// As/Bs LDS (32 KB, dead) is reused as a C tile; fragments are written there
// (XOR-chunk swizzle vs bank conflicts), then stored to global as contiguous
// 16B-coalesced runs (mode 1: per-head 16 KB contiguous region; mode 2:
// 256B runs per (h,d) row).
__global__ __launch_bounds__(256, 3) void qkv_gemm(const unsigned short* __restrict__ xb,
                                                   const unsigned short* __restrict__ Wqb,
                                                   const unsigned short* __restrict__ Wkb,
                                                   const unsigned short* __restrict__ Wvb,
                                                   const float* __restrict__ bq,
                                                   const float* __restrict__ bk,
                                                   const float* __restrict__ bv,
                                                   unsigned short* __restrict__ Qb,
                                                   unsigned short* __restrict__ Kb,
                                                   unsigned short* __restrict__ Vtb) {
  __shared__ unsigned short Sh[2 * 128 * BK];   // As | Bs; reused as C tile in epilogue
  unsigned short* As = Sh;
  unsigned short* Bs = Sh + 128 * BK;

  const int lid = blockIdx.x + 32 * blockIdx.y + 256 * blockIdx.z;
  const int xcd = lid & 7;
  const int seq = lid >> 3;           // 0..95 per XCD
  const int z   = seq >> 5;           // 0..2
  const int ml  = (seq & 31) >> 3;    // 0..3
  const int nb  = seq & 7;            // 0..7
  const int m0 = (xcd * 4 + ml) * 128;
  const int n0 = nb * 128;

  const unsigned short* Bm = (z == 0) ? Wqb : (z == 1) ? Wkb : Wvb;
  const float* bias        = (z == 0) ? bq  : (z == 1) ? bk  : bv;
  unsigned short* outp     = (z == 0) ? Qb  : (z == 1) ? Kb  : Vtb;
  const float scale = (z == 0) ? QSCALE : 1.0f;
  const int mode = (z == 2) ? 2 : 1;

  const int tid  = threadIdx.x;
  const int lane = tid & 63;
  const int wave = tid >> 6;
  const int m16  = lane & 15;
  const int quad = lane >> 4;
  const int wrow = (wave >> 1) * 64;
  const int wcol = (wave & 1) * 64;
  const int K = 1024;

  floatx4 acc[4][4];
  for (int i = 0; i < 4; ++i)
    for (int j = 0; j < 4; ++j) acc[i][j] = floatx4{0.f, 0.f, 0.f, 0.f};

  for (int k0 = 0; k0 < K; k0 += BK) {
    __syncthreads();
    for (int i = 0; i < 4; ++i) {
      int c = i * 256 + tid;
      int row = c >> 3, col = (c & 7) << 3;
      stage16(xb + (size_t)(m0 + row) * K + k0 + col,
              (char*)As + (size_t)(i * 256 + wave * 64) * 16);
      stage16(Bm + (size_t)(n0 + row) * K + k0 + col,
              (char*)Bs + (size_t)(i * 256 + wave * 64) * 16);
    }
    __syncthreads();
    for (int kk = 0; kk < 2; ++kk) {
      bf16x8 af[4], bfr[4];
      for (int ti = 0; ti < 4; ++ti)
        af[ti] = *(const bf16x8*)(As + (wrow + ti * 16 + m16) * BK + kk * 32 + quad * 8);
      for (int tj = 0; tj < 4; ++tj)
        bfr[tj] = *(const bf16x8*)(Bs + (wcol + tj * 16 + m16) * BK + kk * 32 + quad * 8);
      for (int ti = 0; ti < 4; ++ti)
        for (int tj = 0; tj < 4; ++tj)
          acc[ti][tj] = __builtin_amdgcn_mfma_f32_16x16x32_bf16(bfr[tj], af[ti], acc[ti][tj], 0, 0, 0);
    }
  }

  __syncthreads();   // all LDS reads of the last tile done; Sh reusable as C tile
  const int bb = m0 >> 11, ss0 = m0 & 2047;   // 128-row tile never straddles batch

  if (mode == 1) {
    // C tile [m 128][n 128] bf16; 8-col chunks XOR-swizzled: chunk' = chunk ^ (m&7)
    for (int ti = 0; ti < 4; ++ti) {
      int m = wrow + ti * 16 + m16;
      for (int tj = 0; tj < 4; ++tj) {
        int col = wcol + tj * 16 + quad * 4;
        int c8 = col >> 3, off = col & 7;
        float4 b4 = *(const float4*)(bias + n0 + col);
        float v0 = (acc[ti][tj][0] + b4.x) * scale;
        float v1 = (acc[ti][tj][1] + b4.y) * scale;
        float v2 = (acc[ti][tj][2] + b4.z) * scale;
        float v3 = (acc[ti][tj][3] + b4.w) * scale;
        unsigned* cw = (unsigned*)&Sh[m * 128 + ((c8 ^ (m & 7)) << 3) + off];
        cw[0] = packbf2(v0, v1);
        cw[1] = packbf2(v2, v3);
      }
    }
    __syncthreads();
    // store: per head the region [ss0..ss0+128) x [0..64) is 16 KB CONTIGUOUS.
    // 2048 16B-chunks / 256 thr = 8 each; consecutive tid -> consecutive 16B.
    for (int e = 0; e < 8; ++e) {
      int g = e * 256 + tid;
      int hf = g >> 10;               // head half of the 128-col tile
      int gg = g & 1023;
      int m = gg >> 3, c8l = gg & 7;  // row, chunk within head
      uint4v v = *(const uint4v*)&Sh[m * 128 + (((hf * 8 + c8l) ^ (m & 7)) << 3)];
      int hh = (n0 >> 6) + hf;
      unsigned short* dst = outp + ((size_t)(bb * NH + hh) * S_LEN + ss0 + m) * HD + c8l * 8;
      *(uint4v*)dst = v;
    }
  } else {
    // V^T: C tile TRANSPOSED in LDS: [n(d) 128][m(s) 128] bf16;
    // 8-elem m-chunks XOR-swizzled: chunk' = chunk ^ (n&15)
    for (int tj = 0; tj < 4; ++tj)
      for (int reg = 0; reg < 4; ++reg) {
        int n = wcol + tj * 16 + quad * 4 + reg;
        float bv = bias[n0 + n];
        for (int ti = 0; ti < 4; ++ti) {
          int m = wrow + ti * 16 + m16;
          int cm = m >> 3;
          Sh[n * 128 + ((cm ^ (n & 15)) << 3) + (m & 7)] =
              f2bf_hu(acc[ti][tj][reg] + bv);
        }
      }
    __syncthreads();
    // store: per (h,d) row 256B contiguous along s. 2048 chunks / 256 thr = 8.
    for (int e = 0; e < 8; ++e) {
      int g = e * 256 + tid;
      int n = g >> 4, cm = g & 15;
      uint4v v = *(const uint4v*)&Sh[n * 128 + ((cm ^ (n & 15)) << 3)];
      int gn = n0 + n, hh = gn >> 6, d = gn & 63;
      unsigned short* dst = outp + ((size_t)(bb * NH + hh) * HD + d) * S_LEN + ss0 + cm * 8;
      *(uint4v*)dst = v;
    }
  }
}

// Output projection v5 (unchanged from R9): 128x64 tile, 4 waves x 64x32,
// DMA-staged panels, XCD-stripe swizzle. Stores are 64B/16-lane runs (ok).
__global__ __launch_bounds__(256, 4) void out_gemm(const unsigned short* __restrict__ Ab,
                                                   const unsigned short* __restrict__ Wob,
                                                   const float* __restrict__ bo,
                                                   float* __restrict__ out) {
  __shared__ unsigned short As[128 * BK];
  __shared__ unsigned short Bs[64 * BK];
  const int lid = blockIdx.x + 32 * blockIdx.y;
  const int xcd = lid & 7;
  const int seq = lid >> 3;           // 0..63 per XCD
  const int m0 = (xcd * 4 + (seq >> 4)) * 128;
  const int n0 = (seq & 15) * 64;     // fastest: cycles B panels

  const int tid  = threadIdx.x;
  const int lane = tid & 63;
  const int wave = tid >> 6;
  const int m16  = lane & 15;
  const int quad = lane >> 4;
  const int wrow = (wave >> 1) * 64;
  const int wcol = (wave & 1) * 32;
  const int K = 1024, N = 1024;

  floatx4 acc[4][2];
  for (int i = 0; i < 4; ++i)
    for (int j = 0; j < 2; ++j) acc[i][j] = floatx4{0.f, 0.f, 0.f, 0.f};

  for (int k0 = 0; k0 < K; k0 += BK) {
    __syncthreads();
    for (int i = 0; i < 4; ++i) {
      int c = i * 256 + tid;
      int row = c >> 3, col = (c & 7) << 3;
      stage16(Ab + (size_t)(m0 + row) * K + k0 + col,
              (char*)As + (size_t)(i * 256 + wave * 64) * 16);
    }
    for (int i = 0; i < 2; ++i) {
      int c = i * 256 + tid;
      int row = c >> 3, col = (c & 7) << 3;
      stage16(Wob + (size_t)(n0 + row) * K + k0 + col,
              (char*)Bs + (size_t)(i * 256 + wave * 64) * 16);
    }
    __syncthreads();
    for (int kk = 0; kk < 2; ++kk) {
      bf16x8 af[4], bfr[2];
      for (int ti = 0; ti < 4; ++ti)
        af[ti] = *(const bf16x8*)(As + (wrow + ti * 16 + m16) * BK + kk * 32 + quad * 8);
      for (int tj = 0; tj < 2; ++tj)
        bfr[tj] = *(const bf16x8*)(Bs + (wcol + tj * 16 + m16) * BK + kk * 32 + quad * 8);
      for (int ti = 0; ti < 4; ++ti)
        for (int tj = 0; tj < 2; ++tj)
          acc[ti][tj] = __builtin_amdgcn_mfma_f32_16x16x32_bf16(af[ti], bfr[tj], acc[ti][tj], 0, 0, 0);
    }
  }

  for (int tj = 0; tj < 2; ++tj) {
    int n = n0 + wcol + tj * 16 + m16;
    float bv = bo[n];
    for (int ti = 0; ti < 4; ++ti)
      for (int reg = 0; reg < 4; ++reg) {
        int m = m0 + wrow + ti * 16 + quad * 4 + reg;
        out[(size_t)m * N + n] = acc[ti][tj][reg] + bv;
      }
  }
}

// Flash attention v9 (R4's passing version, unchanged): KVBLK=64, 4 waves,
// 32 q-rows/wave (2 Q-frags/wave). global_load_lds DMA, pre-swizzled global
// source, LDS dest linear; double buffer, one barrier/tile. FIXED-REFERENCE
// softmax: p = exp2(s), O = sum(pV)/sum(p); l-reduce deferred to epilogue.
__global__ __launch_bounds__(256, 4) void attn_kernel(const unsigned short* __restrict__ Qb,  // [B,H,S,D] *QSCALE
                                                      const unsigned short* __restrict__ Kb,  // [B,H,S,D]
                                                      const unsigned short* __restrict__ Vtb, // [B,H,D,S]
                                                      const int* __restrict__ mask,           // [B,S]
                                                      unsigned short* __restrict__ attnb) {   // [B,S,E]
  __shared__ unsigned short Ks[2 * 64 * 64];   // [p][kv][d], chunk' = chunk ^ (kv&7), 8 chunks/row
  __shared__ unsigned short Vts[2 * 64 * 64];  // [p][d][kv], chunk' = chunk ^ (d&7), 8 chunks/row
  __shared__ int zw[4];
#ifndef HAVE_MFMA16
  __shared__ unsigned short Pq[4 * 16 * 72];
#endif

  const int tid  = threadIdx.x;
  const int lane = tid & 63;
  const int wave = tid >> 6;          // 0..3
  const int m16  = lane & 15;
  const int quad = lane >> 4;
  const int bh = blockIdx.x;          // fastest -> XCD = bh % 8 (K/V L2-resident per XCD)
  const int qt = blockIdx.y;
  const int b  = bh >> 4;
  const int h  = bh & 15;
  const int q0 = qt * 128;
  const size_t head = (size_t)bh * S_LEN * HD;

  // 2 Q-fragments per wave: rows q0 + wave*32 + qs*16 + m16
  bf16x8 qf[2][2];
  for (int qs = 0; qs < 2; ++qs) {
    const unsigned short* qrow = Qb + head + (size_t)(q0 + wave * 32 + qs * 16 + m16) * HD;
    qf[qs][0] = *(const bf16x8*)(qrow + quad * 8);
    qf[qs][1] = *(const bf16x8*)(qrow + 32 + quad * 8);
  }

  // DMA source addresses (LDS dest linear; XOR swizzle folded into the global
  // per-lane address). Wave w owns rows [w*16, w*16+16) of each 64-row tile.
  const int kr = lane >> 3, kc = lane & 7;
  const unsigned short* kg0 = Kb + head + (size_t)(wave * 16 + kr) * HD + ((kc ^ kr) << 3);
  const unsigned short* vg0 = Vtb + head + (size_t)(wave * 16 + kr) * S_LEN + ((kc ^ kr) << 3);
  const int* mrow = mask + b * S_LEN;

#define STAGE_KV(pp, kb_)                                                      \
  {                                                                            \
    const unsigned short* ksrc = kg0 + (size_t)(kb_) * 64 * HD;                \
    char* kdst = (char*)Ks + (pp) * 8192 + wave * 2048;                        \
    stage16(ksrc,           kdst);                                             \
    stage16(ksrc + 8 * HD,  kdst + 1024);                                      \
    const unsigned short* vsrc = vg0 + (kb_) * 64;                             \
    char* vdst = (char*)Vts + (pp) * 8192 + wave * 2048;                       \
    stage16(vsrc,              vdst);                                          \
    stage16(vsrc + 8 * S_LEN,  vdst + 1024);                                   \
  }

  float l_run[2] = {0.f, 0.f};   // per-lane partial; cross-lane reduce deferred
  floatx4 acc_o[2][4];
  for (int qs = 0; qs < 2; ++qs)
    for (int ti = 0; ti < 4; ++ti) acc_o[qs][ti] = floatx4{0.f, 0.f, 0.f, 0.f};

  // one-time block-wide mask scan (2048 ints / 256 thr = 2 int4 each)
  {
    const int4* mp = (const int4*)(mrow + tid * 8);
    int4 a = mp[0], c4 = mp[1];
    bool z = (a.x & a.y & a.z & a.w & c4.x & c4.y & c4.z & c4.w) == 0;  // mask values are 0/1
    unsigned long long bal = __ballot(z);
    if (lane == 0) zw[wave] = (bal != 0ull) ? 1 : 0;
  }

  STAGE_KV(0, 0);
  __syncthreads();   // drains vmcnt(0): tile 0 resident; zw visible
  const bool anymask = (zw[0] | zw[1] | zw[2] | zw[3]) != 0;

  const int xs = m16 & 7;
  const floatx4 fz = floatx4{0.f, 0.f, 0.f, 0.f};

  for (int kb = 0; kb < 32; ++kb) {
    const int p = kb & 1;
    const unsigned short* Kp = Ks + p * 4096;
    const unsigned short* Vp = Vts + p * 4096;
    if (kb < 31) STAGE_KV(p ^ 1, kb + 1);   // async into the other buffer

    // S^T[kv][q]: A = K fragment (m=kv), B = Q fragment (n=q). Each K frag
    // feeds both q-sets.
    floatx4 acc_s[2][4];
    {
      bf16x8 kf[4];
      for (int tj = 0; tj < 4; ++tj)
        kf[tj] = *(const bf16x8*)&Kp[(tj * 16 + m16) * 64 + ((quad ^ xs) << 3)];
      for (int tj = 0; tj < 4; ++tj) {
        acc_s[0][tj] = __builtin_amdgcn_mfma_f32_16x16x32_bf16(kf[tj], qf[0][0], fz, 0, 0, 0);
        acc_s[1][tj] = __builtin_amdgcn_mfma_f32_16x16x32_bf16(kf[tj], qf[1][0], fz, 0, 0, 0);
      }
      for (int tj = 0; tj < 4; ++tj)
        kf[tj] = *(const bf16x8*)&Kp[(tj * 16 + m16) * 64 + (((4 + quad) ^ xs) << 3)];
      for (int tj = 0; tj < 4; ++tj) {
        acc_s[0][tj] = __builtin_amdgcn_mfma_f32_16x16x32_bf16(kf[tj], qf[0][1], acc_s[0][tj], 0, 0, 0);
        acc_s[1][tj] = __builtin_amdgcn_mfma_f32_16x16x32_bf16(kf[tj], qf[1][1], acc_s[1][tj], 0, 0, 0);
      }
    }

    unsigned up[2][8];
    for (int qs = 0; qs < 2; ++qs) {
      if (anymask) {
        for (int t = 0; t < 4; ++t)
          for (int r = 0; r < 4; ++r) {
            int idx = kb * 64 + t * 16 + quad * 4 + r;
            acc_s[qs][t][r] += (mrow[idx] == 0) ? -1e9f : 0.f;
          }
      }
      float sl = 0.f;
      for (int i = 0; i < 8; ++i) {
        float p0 = EXP2F(acc_s[qs][i >> 1][(i & 1) * 2]);
        float p1 = EXP2F(acc_s[qs][i >> 1][(i & 1) * 2 + 1]);
        sl += p0 + p1;
        up[qs][i] = packbf2(p0, p1);
      }
      l_run[qs] += sl;   // per-lane partial (covers this lane's kv subset)
    }

#ifdef HAVE_MFMA16
    for (int ti = 0; ti < 4; ++ti)
      for (int c = 0; c < 4; ++c) {
        short4v vf = *(const short4v*)&Vp[(ti * 16 + m16) * 64 +
                                          (((2 * c + (quad >> 1)) ^ xs) << 3) +
                                          ((quad & 1) << 2)];
        short4v Pb0 = __builtin_bit_cast(short4v, uint2v{up[0][2 * c], up[0][2 * c + 1]});
        short4v Pb1 = __builtin_bit_cast(short4v, uint2v{up[1][2 * c], up[1][2 * c + 1]});
        acc_o[0][ti] = __builtin_amdgcn_mfma_f32_16x16x16bf16_1k(vf, Pb0, acc_o[0][ti], 0, 0, 0);
        acc_o[1][ti] = __builtin_amdgcn_mfma_f32_16x16x16bf16_1k(vf, Pb1, acc_o[1][ti], 0, 0, 0);
      }
#else
    // host-parse / non-gfx950 fallback: per-wave LDS round-trip + x32
    {
      unsigned short* Pw = Pq + wave * 16 * 72;
      for (int qs = 0; qs < 2; ++qs) {
        for (int t = 0; t < 4; ++t) {
          *(unsigned*)&Pw[m16 * 72 + t * 16 + quad * 4]     = up[qs][2 * t];
          *(unsigned*)&Pw[m16 * 72 + t * 16 + quad * 4 + 2] = up[qs][2 * t + 1];
        }
        for (int kk = 0; kk < 2; ++kk) {
          bf16x8 pf = *(const bf16x8*)&Pw[m16 * 72 + kk * 32 + quad * 8];
          for (int ti = 0; ti < 4; ++ti) {
            bf16x8 vfb = *(const bf16x8*)&Vp[(ti * 16 + m16) * 64 +
                                             (((kk * 4 + quad) ^ xs) << 3)];
            acc_o[qs][ti] = __builtin_amdgcn_mfma_f32_16x16x32_bf16(vfb, pf, acc_o[qs][ti], 0, 0, 0);
          }
        }
      }
    }
#endif

    __syncthreads();   // readers of buf p done; DMA for p^1 drained (vmcnt 0)
  }

  for (int qs = 0; qs < 2; ++qs) {
    // deferred cross-lane reduce: q-row sum lives on lanes m16, +16, +32, +48
    l_run[qs] += __shfl_xor(l_run[qs], 16);
    l_run[qs] += __shfl_xor(l_run[qs], 32);
    float rl = 1.f / l_run[qs];
    int orow = q0 + wave * 32 + qs * 16 + m16;
    for (int ti = 0; ti < 4; ++ti) {
      ushort4 o;
      o.x = f2bf_hu(acc_o[qs][ti][0] * rl);
      o.y = f2bf_hu(acc_o[qs][ti][1] * rl);
      o.z = f2bf_hu(acc_o[qs][ti][2] * rl);
      o.w = f2bf_hu(acc_o[qs][ti][3] * rl);
      int e = h * HD + ti * 16 + quad * 4;
      *(ushort4*)&attnb[((size_t)(b * S_LEN + orow)) * EMB + e] = o;
    }
  }
#undef STAGE_KV
}

extern "C" void kernel_launch(void* const* d_in, const int* in_sizes, int n_in,
                              void* d_out, int out_size, void* d_ws, size_t ws_size,
                              hipStream_t stream) {
  const float* x  = (const float*)d_in[0];
  const int* mask = (const int*)d_in[1];
  const float* Wq = (const float*)d_in[2];
  const float* bq = (const float*)d_in[3];
  const float* Wk = (const float*)d_in[4];
  const float* bk = (const float*)d_in[5];
  const float* Wv = (const float*)d_in[6];
  const float* bv = (const float*)d_in[7];
  const float* Wo = (const float*)d_in[8];
  const float* bo = (const float*)d_in[9];
  float* out = (float*)d_out;

  // Workspace overlay: Ab reuses xb's region — xb is dead after qkv_gemm and
  // kernels are stream-serialized (cvt -> qkv -> attn -> out). ws use 48->40 MB.
  char* ws = (char*)d_ws;
  unsigned short* xb  = (unsigned short*)(ws);               // 8 MB (cvt->qkv)
  unsigned short* Ab  = (unsigned short*)(ws);               // 8 MB (attn->out), overlays xb
  unsigned short* Wqb = (unsigned short*)(ws + 8388608);     // 2 MB
  unsigned short* Wkb = (unsigned short*)(ws + 10485760);    // 2 MB
  unsigned short* Wvb = (unsigned short*)(ws + 12582912);    // 2 MB
  unsigned short* Wob = (unsigned short*)(ws + 14680064);    // 2 MB
  unsigned short* Qb  = (unsigned short*)(ws + 16777216);    // 8 MB [B,H,S,D]
  unsigned short* Kbb = (unsigned short*)(ws + 25165824);    // 8 MB [B,H,S,D]
  unsigned short* Vtb = (unsigned short*)(ws + 33554432);    // 8 MB [B,H,D,S] (end 40 MB)

  cvt_all<<<dim3(8192), dim3(256), 0, stream>>>(x, Wq, Wk, Wv, Wo, xb, Wqb, Wkb, Wvb, Wob);
  qkv_gemm<<<dim3(32, 8, 3), dim3(256), 0, stream>>>(xb, Wqb, Wkb, Wvb, bq, bk, bv, Qb, Kbb, Vtb);
  attn_kernel<<<dim3(32, 16), dim3(256), 0, stream>>>(Qb, Kbb, Vtb, mask, Ab);
  out_gemm<<<dim3(32, 16), dim3(256), 0, stream>>>(Ab, Wob, bo, out);
}

// Round 11
// 198.722 us; speedup vs baseline: 1.0842x; 1.0068x over previous
//
#include <hip/hip_runtime.h>
#include <stdint.h>

#define S_LEN 2048
#define EMB   1024
#define NH    16
#define HD    64
#define BK 64

typedef __bf16 bf16x8 __attribute__((ext_vector_type(8)));
typedef short  short4v __attribute__((ext_vector_type(4)));
typedef unsigned int uint2v __attribute__((ext_vector_type(2)));
typedef unsigned int uint4v __attribute__((ext_vector_type(4)));
typedef float  floatx4 __attribute__((ext_vector_type(4)));

// Guards need compilable fallbacks: the HIP host pass reports no amdgcn builtins.
#if defined(__has_builtin)
#if __has_builtin(__builtin_amdgcn_mfma_f32_16x16x16bf16_1k)
#define HAVE_MFMA16 1
#endif
#if __has_builtin(__builtin_amdgcn_exp2f)
#define EXP2F __builtin_amdgcn_exp2f   // single v_exp_f32 (quarter-rate) — NOT ocml exp2f
#endif
#endif
#ifndef EXP2F
#define EXP2F exp2f
#endif

#if defined(__has_builtin)
#if __has_builtin(__builtin_amdgcn_s_setprio)
#define SETPRIO(x) __builtin_amdgcn_s_setprio(x)
#endif
#endif
#ifndef SETPRIO
#define SETPRIO(x)
#endif

// 0.125 (1/sqrt(64)) * log2(e): Q pre-scale so softmax runs in exp2 domain
#define QSCALE 0.1803368801111204f

__device__ __forceinline__ unsigned short f2bf(float f) {
  unsigned u = __builtin_bit_cast(unsigned, f);
  u += 0x7fffu + ((u >> 16) & 1u);   // RNE
  return (unsigned short)(u >> 16);
}
__device__ __forceinline__ unsigned short f2bf_hu(float f) {
  return (unsigned short)((__builtin_bit_cast(unsigned, f) + 0x8000u) >> 16);
}
// pack 2 floats -> [bf16(b):bf16(a)] via v_perm, half-up.
// NOTE (R7): v_cvt_pk_bf16_f32 inline-asm FAILED correctness — keep v_perm path.
__device__ __forceinline__ unsigned packbf2(float a, float b) {
  unsigned ua = __builtin_bit_cast(unsigned, a) + 0x8000u;
  unsigned ub = __builtin_bit_cast(unsigned, b) + 0x8000u;
  return __builtin_amdgcn_perm(ub, ua, 0x07060302);
}

__global__ __launch_bounds__(256) void cvt_all(const float* __restrict__ x,
                                               const float* __restrict__ Wq,
                                               const float* __restrict__ Wk,
                                               const float* __restrict__ Wv,
                                               const float* __restrict__ Wo,
                                               unsigned short* __restrict__ xb,
                                               unsigned short* __restrict__ Wqb,
                                               unsigned short* __restrict__ Wkb,
                                               unsigned short* __restrict__ Wvb,
                                               unsigned short* __restrict__ Wob) {
  int blk = blockIdx.x;
  const float* s; unsigned short* d; int off;
  if (blk < 4096)      { s = x;  d = xb;  off = blk; }
  else if (blk < 5120) { s = Wq; d = Wqb; off = blk - 4096; }
  else if (blk < 6144) { s = Wk; d = Wkb; off = blk - 5120; }
  else if (blk < 7168) { s = Wv; d = Wvb; off = blk - 6144; }
  else                 { s = Wo; d = Wob; off = blk - 7168; }
  int i = (off * 256 + threadIdx.x) * 4;
  float4 v = *(const float4*)(s + i);
  ushort4 o;
  o.x = f2bf(v.x); o.y = f2bf(v.y); o.z = f2bf(v.z); o.w = f2bf(v.w);
  *(ushort4*)(d + i) = o;
}

__device__ __forceinline__ void stage16(const void* g, void* l) {
  __builtin_amdgcn_global_load_lds(
      (const __attribute__((address_space(1))) void*)g,
      (__attribute__((address_space(3))) void*)l, 16, 0, 0);
}

// QKV projection v4 (unchanged from R10, passing): 128x128 tile, XCD-stripe
// swizzle, LDS-staged coalesced epilogue.
__global__ __launch_bounds__(256, 3) void qkv_gemm(const unsigned short* __restrict__ xb,
                                                   const unsigned short* __restrict__ Wqb,
                                                   const unsigned short* __restrict__ Wkb,
                                                   const unsigned short* __restrict__ Wvb,
                                                   const float* __restrict__ bq,
                                                   const float* __restrict__ bk,
                                                   const float* __restrict__ bv,
                                                   unsigned short* __restrict__ Qb,
                                                   unsigned short* __restrict__ Kb,
                                                   unsigned short* __restrict__ Vtb) {
  __shared__ unsigned short Sh[2 * 128 * BK];   // As | Bs; reused as C tile in epilogue
  unsigned short* As = Sh;
  unsigned short* Bs = Sh + 128 * BK;

  const int lid = blockIdx.x + 32 * blockIdx.y + 256 * blockIdx.z;
  const int xcd = lid & 7;
  const int seq = lid >> 3;           // 0..95 per XCD
  const int z   = seq >> 5;           // 0..2
  const int ml  = (seq & 31) >> 3;    // 0..3
  const int nb  = seq & 7;            // 0..7
  const int m0 = (xcd * 4 + ml) * 128;
  const int n0 = nb * 128;

  const unsigned short* Bm = (z == 0) ? Wqb : (z == 1) ? Wkb : Wvb;
  const float* bias        = (z == 0) ? bq  : (z == 1) ? bk  : bv;
  unsigned short* outp     = (z == 0) ? Qb  : (z == 1) ? Kb  : Vtb;
  const float scale = (z == 0) ? QSCALE : 1.0f;
  const int mode = (z == 2) ? 2 : 1;

  const int tid  = threadIdx.x;
  const int lane = tid & 63;
  const int wave = tid >> 6;
  const int m16  = lane & 15;
  const int quad = lane >> 4;
  const int wrow = (wave >> 1) * 64;
  const int wcol = (wave & 1) * 64;
  const int K = 1024;

  floatx4 acc[4][4];
  for (int i = 0; i < 4; ++i)
    for (int j = 0; j < 4; ++j) acc[i][j] = floatx4{0.f, 0.f, 0.f, 0.f};

  for (int k0 = 0; k0 < K; k0 += BK) {
    __syncthreads();
    for (int i = 0; i < 4; ++i) {
      int c = i * 256 + tid;
      int row = c >> 3, col = (c & 7) << 3;
      stage16(xb + (size_t)(m0 + row) * K + k0 + col,
              (char*)As + (size_t)(i * 256 + wave * 64) * 16);
      stage16(Bm + (size_t)(n0 + row) * K + k0 + col,
              (char*)Bs + (size_t)(i * 256 + wave * 64) * 16);
    }
    __syncthreads();
    for (int kk = 0; kk < 2; ++kk) {
      bf16x8 af[4], bfr[4];
      for (int ti = 0; ti < 4; ++ti)
        af[ti] = *(const bf16x8*)(As + (wrow + ti * 16 + m16) * BK + kk * 32 + quad * 8);
      for (int tj = 0; tj < 4; ++tj)
        bfr[tj] = *(const bf16x8*)(Bs + (wcol + tj * 16 + m16) * BK + kk * 32 + quad * 8);
      for (int ti = 0; ti < 4; ++ti)
        for (int tj = 0; tj < 4; ++tj)
          acc[ti][tj] = __builtin_amdgcn_mfma_f32_16x16x32_bf16(bfr[tj], af[ti], acc[ti][tj], 0, 0, 0);
    }
  }

  __syncthreads();   // all LDS reads of the last tile done; Sh reusable as C tile
  const int bb = m0 >> 11, ss0 = m0 & 2047;   // 128-row tile never straddles batch

  if (mode == 1) {
    // C tile [m 128][n 128] bf16; 8-col chunks XOR-swizzled: chunk' = chunk ^ (m&7)
    for (int ti = 0; ti < 4; ++ti) {
      int m = wrow + ti * 16 + m16;
      for (int tj = 0; tj < 4; ++tj) {
        int col = wcol + tj * 16 + quad * 4;
        int c8 = col >> 3, off = col & 7;
        float4 b4 = *(const float4*)(bias + n0 + col);
        float v0 = (acc[ti][tj][0] + b4.x) * scale;
        float v1 = (acc[ti][tj][1] + b4.y) * scale;
        float v2 = (acc[ti][tj][2] + b4.z) * scale;
        float v3 = (acc[ti][tj][3] + b4.w) * scale;
        unsigned* cw = (unsigned*)&Sh[m * 128 + ((c8 ^ (m & 7)) << 3) + off];
        cw[0] = packbf2(v0, v1);
        cw[1] = packbf2(v2, v3);
      }
    }
    __syncthreads();
    for (int e = 0; e < 8; ++e) {
      int g = e * 256 + tid;
      int hf = g >> 10;               // head half of the 128-col tile
      int gg = g & 1023;
      int m = gg >> 3, c8l = gg & 7;  // row, chunk within head
      uint4v v = *(const uint4v*)&Sh[m * 128 + (((hf * 8 + c8l) ^ (m & 7)) << 3)];
      int hh = (n0 >> 6) + hf;
      unsigned short* dst = outp + ((size_t)(bb * NH + hh) * S_LEN + ss0 + m) * HD + c8l * 8;
      *(uint4v*)dst = v;
    }
  } else {
    // V^T: C tile TRANSPOSED in LDS: [n(d) 128][m(s) 128] bf16;
    // 8-elem m-chunks XOR-swizzled: chunk' = chunk ^ (n&15)
    for (int tj = 0; tj < 4; ++tj)
      for (int reg = 0; reg < 4; ++reg) {
        int n = wcol + tj * 16 + quad * 4 + reg;
        float bv = bias[n0 + n];
        for (int ti = 0; ti < 4; ++ti) {
          int m = wrow + ti * 16 + m16;
          int cm = m >> 3;
          Sh[n * 128 + ((cm ^ (n & 15)) << 3) + (m & 7)] =
              f2bf_hu(acc[ti][tj][reg] + bv);
        }
      }
    __syncthreads();
    for (int e = 0; e < 8; ++e) {
      int g = e * 256 + tid;
      int n = g >> 4, cm = g & 15;
      uint4v v = *(const uint4v*)&Sh[n * 128 + ((cm ^ (n & 15)) << 3)];
      int gn = n0 + n, hh = gn >> 6, d = gn & 63;
      unsigned short* dst = outp + ((size_t)(bb * NH + hh) * HD + d) * S_LEN + ss0 + cm * 8;
      *(uint4v*)dst = v;
    }
  }
}

// Output projection v5 (unchanged from R10): 128x64 tile, 4 waves x 64x32,
// DMA-staged panels, XCD-stripe swizzle.
__global__ __launch_bounds__(256, 4) void out_gemm(const unsigned short* __restrict__ Ab,
                                                   const unsigned short* __restrict__ Wob,
                                                   const float* __restrict__ bo,
                                                   float* __restrict__ out) {
  __shared__ unsigned short As[128 * BK];
  __shared__ unsigned short Bs[64 * BK];
  const int lid = blockIdx.x + 32 * blockIdx.y;
  const int xcd = lid & 7;
  const int seq = lid >> 3;           // 0..63 per XCD
  const int m0 = (xcd * 4 + (seq >> 4)) * 128;
  const int n0 = (seq & 15) * 64;     // fastest: cycles B panels

  const int tid  = threadIdx.x;
  const int lane = tid & 63;
  const int wave = tid >> 6;
  const int m16  = lane & 15;
  const int quad = lane >> 4;
  const int wrow = (wave >> 1) * 64;
  const int wcol = (wave & 1) * 32;
  const int K = 1024, N = 1024;

  floatx4 acc[4][2];
  for (int i = 0; i < 4; ++i)
    for (int j = 0; j < 2; ++j) acc[i][j] = floatx4{0.f, 0.f, 0.f, 0.f};

  for (int k0 = 0; k0 < K; k0 += BK) {
    __syncthreads();
    for (int i = 0; i < 4; ++i) {
      int c = i * 256 + tid;
      int row = c >> 3, col = (c & 7) << 3;
      stage16(Ab + (size_t)(m0 + row) * K + k0 + col,
              (char*)As + (size_t)(i * 256 + wave * 64) * 16);
    }
    for (int i = 0; i < 2; ++i) {
      int c = i * 256 + tid;
      int row = c >> 3, col = (c & 7) << 3;
      stage16(Wob + (size_t)(n0 + row) * K + k0 + col,
              (char*)Bs + (size_t)(i * 256 + wave * 64) * 16);
    }
    __syncthreads();
    for (int kk = 0; kk < 2; ++kk) {
      bf16x8 af[4], bfr[2];
      for (int ti = 0; ti < 4; ++ti)
        af[ti] = *(const bf16x8*)(As + (wrow + ti * 16 + m16) * BK + kk * 32 + quad * 8);
      for (int tj = 0; tj < 2; ++tj)
        bfr[tj] = *(const bf16x8*)(Bs + (wcol + tj * 16 + m16) * BK + kk * 32 + quad * 8);
      for (int ti = 0; ti < 4; ++ti)
        for (int tj = 0; tj < 2; ++tj)
          acc[ti][tj] = __builtin_amdgcn_mfma_f32_16x16x32_bf16(af[ti], bfr[tj], acc[ti][tj], 0, 0, 0);
    }
  }

  for (int tj = 0; tj < 2; ++tj) {
    int n = n0 + wcol + tj * 16 + m16;
    float bv = bo[n];
    for (int ti = 0; ti < 4; ++ti)
      for (int reg = 0; reg < 4; ++reg) {
        int m = m0 + wrow + ti * 16 + quad * 4 + reg;
        out[(size_t)m * N + n] = acc[ti][tj][reg] + bv;
      }
  }
}

// Flash attention v11: CROSS-TILE SOFTWARE PIPELINE (T15-style, measured
// +7-11% in learn_hip m214v36) + setprio (T5, attn +4-7% m191).
// R10 diagnosis: per-tile serial chain QK->exp2->pack->PV leaves ~29% issue
// idle (MfmaUtil 33 + VALUBusy 38); TLP can't fill it (R6: 2x waves -> -5%).
// Restructure: QK(kb+1) issues BEFORE softmax(kb), so tile kb+1's MFMAs run
// on the matrix pipe while the VALU does tile kb's exp2, and softmax never
// waits on just-issued MFMAs. Requires K/V staged 2 tiles ahead -> TRIPLE
// buffer (3x16KB = 48KB LDS, <=3 blocks/CU). Accumulators ping-pong with
// STATIC names (accA/accB, hand-unrolled x2 body — rule #20: no runtime
// indexing). Slot rotation: tile k lives in slot k%3; every read of a slot
// completes before the barrier preceding its overwrite (verified: slot
// overwritten at tile k+3's stage, last read at tile k's PV, 2 barriers apart).
__global__ __launch_bounds__(256, 2) void attn_kernel(const unsigned short* __restrict__ Qb,  // [B,H,S,D] *QSCALE
                                                      const unsigned short* __restrict__ Kb,  // [B,H,S,D]
                                                      const unsigned short* __restrict__ Vtb, // [B,H,D,S]
                                                      const int* __restrict__ mask,           // [B,S]
                                                      unsigned short* __restrict__ attnb) {   // [B,S,E]
  __shared__ unsigned short Ks[3 * 64 * 64];   // [slot][kv][d], chunk' = chunk ^ (kv&7)
  __shared__ unsigned short Vts[3 * 64 * 64];  // [slot][d][kv], chunk' = chunk ^ (d&7)
  __shared__ int zw[4];
#ifndef HAVE_MFMA16
  __shared__ unsigned short Pq[4 * 16 * 72];
#endif

  const int tid  = threadIdx.x;
  const int lane = tid & 63;
  const int wave = tid >> 6;          // 0..3
  const int m16  = lane & 15;
  const int quad = lane >> 4;
  const int bh = blockIdx.x;          // fastest -> XCD = bh % 8 (K/V L2-resident per XCD)
  const int qt = blockIdx.y;
  const int b  = bh >> 4;
  const int h  = bh & 15;
  const int q0 = qt * 128;
  const size_t head = (size_t)bh * S_LEN * HD;

  // 2 Q-fragments per wave: rows q0 + wave*32 + qs*16 + m16
  bf16x8 qf[2][2];
  for (int qs = 0; qs < 2; ++qs) {
    const unsigned short* qrow = Qb + head + (size_t)(q0 + wave * 32 + qs * 16 + m16) * HD;
    qf[qs][0] = *(const bf16x8*)(qrow + quad * 8);
    qf[qs][1] = *(const bf16x8*)(qrow + 32 + quad * 8);
  }

  // DMA source addresses (LDS dest linear; XOR swizzle folded into the global
  // per-lane address). Wave w owns rows [w*16, w*16+16) of each 64-row tile.
  const int kr = lane >> 3, kc = lane & 7;
  const unsigned short* kg0 = Kb + head + (size_t)(wave * 16 + kr) * HD + ((kc ^ kr) << 3);
  const unsigned short* vg0 = Vtb + head + (size_t)(wave * 16 + kr) * S_LEN + ((kc ^ kr) << 3);
  const int* mrow = mask + b * S_LEN;

#define STAGE_KV(pp, kb_)                                                      \
  {                                                                            \
    const unsigned short* ksrc = kg0 + (size_t)(kb_) * 64 * HD;                \
    char* kdst = (char*)Ks + (pp) * 8192 + wave * 2048;                        \
    stage16(ksrc,           kdst);                                             \
    stage16(ksrc + 8 * HD,  kdst + 1024);                                      \
    const unsigned short* vsrc = vg0 + (kb_) * 64;                             \
    char* vdst = (char*)Vts + (pp) * 8192 + wave * 2048;                       \
    stage16(vsrc,              vdst);                                          \
    stage16(vsrc + 8 * S_LEN,  vdst + 1024);                                   \
  }

  float l_run[2] = {0.f, 0.f};   // per-lane partial; cross-lane reduce deferred
  floatx4 acc_o[2][4];
  for (int qs = 0; qs < 2; ++qs)
    for (int ti = 0; ti < 4; ++ti) acc_o[qs][ti] = floatx4{0.f, 0.f, 0.f, 0.f};

  // one-time block-wide mask scan (2048 ints / 256 thr = 2 int4 each)
  {
    const int4* mp = (const int4*)(mrow + tid * 8);
    int4 a = mp[0], c4 = mp[1];
    bool z = (a.x & a.y & a.z & a.w & c4.x & c4.y & c4.z & c4.w) == 0;  // mask values are 0/1
    unsigned long long bal = __ballot(z);
    if (lane == 0) zw[wave] = (bal != 0ull) ? 1 : 0;
  }

  const int xs = m16 & 7;
  const floatx4 fz = floatx4{0.f, 0.f, 0.f, 0.f};

  // S^T[kv][q] for one 64-kv tile: A = K fragment (m=kv), B = Q fragment (n=q)
  auto qk_tile = [&](floatx4 (&as)[2][4], const unsigned short* Kp) {
    bf16x8 kf[4];
    SETPRIO(1);
    for (int tj = 0; tj < 4; ++tj)
      kf[tj] = *(const bf16x8*)&Kp[(tj * 16 + m16) * 64 + ((quad ^ xs) << 3)];
    for (int tj = 0; tj < 4; ++tj) {
      as[0][tj] = __builtin_amdgcn_mfma_f32_16x16x32_bf16(kf[tj], qf[0][0], fz, 0, 0, 0);
      as[1][tj] = __builtin_amdgcn_mfma_f32_16x16x32_bf16(kf[tj], qf[1][0], fz, 0, 0, 0);
    }
    for (int tj = 0; tj < 4; ++tj)
      kf[tj] = *(const bf16x8*)&Kp[(tj * 16 + m16) * 64 + (((4 + quad) ^ xs) << 3)];
    for (int tj = 0; tj < 4; ++tj) {
      as[0][tj] = __builtin_amdgcn_mfma_f32_16x16x32_bf16(kf[tj], qf[0][1], as[0][tj], 0, 0, 0);
      as[1][tj] = __builtin_amdgcn_mfma_f32_16x16x32_bf16(kf[tj], qf[1][1], as[1][tj], 0, 0, 0);
    }
    SETPRIO(0);
  };

  auto softmax_tile = [&](floatx4 (&as)[2][4], int kb, unsigned (&up)[2][8]) {
    const bool am = (zw[0] | zw[1] | zw[2] | zw[3]) != 0;
    for (int qs = 0; qs < 2; ++qs) {
      if (am) {
        for (int t = 0; t < 4; ++t)
          for (int r = 0; r < 4; ++r) {
            int idx = kb * 64 + t * 16 + quad * 4 + r;
            as[qs][t][r] += (mrow[idx] == 0) ? -1e9f : 0.f;
          }
      }
      float sl = 0.f;
      for (int i = 0; i < 8; ++i) {
        float p0 = EXP2F(as[qs][i >> 1][(i & 1) * 2]);
        float p1 = EXP2F(as[qs][i >> 1][(i & 1) * 2 + 1]);
        sl += p0 + p1;
        up[qs][i] = packbf2(p0, p1);
      }
      l_run[qs] += sl;
    }
  };

  auto pv_tile = [&](unsigned (&up)[2][8], const unsigned short* Vp) {
#ifdef HAVE_MFMA16
    SETPRIO(1);
    for (int ti = 0; ti < 4; ++ti)
      for (int c = 0; c < 4; ++c) {
        short4v vf = *(const short4v*)&Vp[(ti * 16 + m16) * 64 +
                                          (((2 * c + (quad >> 1)) ^ xs) << 3) +
                                          ((quad & 1) << 2)];
        short4v Pb0 = __builtin_bit_cast(short4v, uint2v{up[0][2 * c], up[0][2 * c + 1]});
        short4v Pb1 = __builtin_bit_cast(short4v, uint2v{up[1][2 * c], up[1][2 * c + 1]});
        acc_o[0][ti] = __builtin_amdgcn_mfma_f32_16x16x16bf16_1k(vf, Pb0, acc_o[0][ti], 0, 0, 0);
        acc_o[1][ti] = __builtin_amdgcn_mfma_f32_16x16x16bf16_1k(vf, Pb1, acc_o[1][ti], 0, 0, 0);
      }
    SETPRIO(0);
#else
    // host-parse / non-gfx950 fallback: per-wave LDS round-trip + x32
    unsigned short* Pw = Pq + wave * 16 * 72;
    for (int qs = 0; qs < 2; ++qs) {
      for (int t = 0; t < 4; ++t) {
        *(unsigned*)&Pw[m16 * 72 + t * 16 + quad * 4]     = up[qs][2 * t];
        *(unsigned*)&Pw[m16 * 72 + t * 16 + quad * 4 + 2] = up[qs][2 * t + 1];
      }
      for (int kk = 0; kk < 2; ++kk) {
        bf16x8 pf = *(const bf16x8*)&Pw[m16 * 72 + kk * 32 + quad * 8];
        for (int ti = 0; ti < 4; ++ti) {
          bf16x8 vfb = *(const bf16x8*)&Vp[(ti * 16 + m16) * 64 +
                                           (((kk * 4 + quad) ^ xs) << 3)];
          acc_o[qs][ti] = __builtin_amdgcn_mfma_f32_16x16x32_bf16(vfb, pf, acc_o[qs][ti], 0, 0, 0);
        }
      }
    }
#endif
  };

  // prologue: stage tiles 0,1; one barrier drains both (implicit vmcnt(0))
  STAGE_KV(0, 0);
  STAGE_KV(1, 1);
  __syncthreads();

  floatx4 accA[2][4], accB[2][4];   // static names: no runtime indexing (rule #20)
  unsigned upA[2][8], upB[2][8];
  qk_tile(accA, Ks + 0 * 4096);     // S(tile 0)

  int scur = 0, snxt = 1, sstg = 2;
  for (int it = 0; it < 16; ++it) {
    // ---- even tile kbE = 2*it: consume accA, produce accB = S(kbE+1)
    {
      const int kbE = it * 2;
      if (it < 15) STAGE_KV(sstg, kbE + 2);           // tile kbE+2 -> slot sstg
      qk_tile(accB, Ks + snxt * 4096);                // S(kbE+1): MFMA runs async...
      softmax_tile(accA, kbE, upA);                   // ...while VALU does exp2(kbE)
      pv_tile(upA, Vts + scur * 4096);                // PV(kbE)
      __syncthreads();                                // drains stage; tile kbE+2 resident
      int t = scur; scur = snxt; snxt = sstg; sstg = t;
    }
    // ---- odd tile kbO = 2*it+1: consume accB, produce accA = S(kbO+1)
    {
      const int kbO = it * 2 + 1;
      if (it < 15) STAGE_KV(sstg, kbO + 2);           // tile kbO+2 -> slot sstg
      if (it < 15) qk_tile(accA, Ks + snxt * 4096);   // S(kbO+1); none after tile 31
      softmax_tile(accB, kbO, upB);
      pv_tile(upB, Vts + scur * 4096);
      __syncthreads();
      int t = scur; scur = snxt; snxt = sstg; sstg = t;
    }
  }

  for (int qs = 0; qs < 2; ++qs) {
    // deferred cross-lane reduce: q-row sum lives on lanes m16, +16, +32, +48
    l_run[qs] += __shfl_xor(l_run[qs], 16);
    l_run[qs] += __shfl_xor(l_run[qs], 32);
    float rl = 1.f / l_run[qs];
    int orow = q0 + wave * 32 + qs * 16 + m16;
    for (int ti = 0; ti < 4; ++ti) {
      ushort4 o;
      o.x = f2bf_hu(acc_o[qs][ti][0] * rl);
      o.y = f2bf_hu(acc_o[qs][ti][1] * rl);
      o.z = f2bf_hu(acc_o[qs][ti][2] * rl);
      o.w = f2bf_hu(acc_o[qs][ti][3] * rl);
      int e = h * HD + ti * 16 + quad * 4;
      *(ushort4*)&attnb[((size_t)(b * S_LEN + orow)) * EMB + e] = o;
    }
  }
#undef STAGE_KV
}

extern "C" void kernel_launch(void* const* d_in, const int* in_sizes, int n_in,
                              void* d_out, int out_size, void* d_ws, size_t ws_size,
                              hipStream_t stream) {
  const float* x  = (const float*)d_in[0];
  const int* mask = (const int*)d_in[1];
  const float* Wq = (const float*)d_in[2];
  const float* bq = (const float*)d_in[3];
  const float* Wk = (const float*)d_in[4];
  const float* bk = (const float*)d_in[5];
  const float* Wv = (const float*)d_in[6];
  const float* bv = (const float*)d_in[7];
  const float* Wo = (const float*)d_in[8];
  const float* bo = (const float*)d_in[9];
  float* out = (float*)d_out;

  // Workspace overlay: Ab reuses xb's region — xb is dead after qkv_gemm and
  // kernels are stream-serialized (cvt -> qkv -> attn -> out).
  char* ws = (char*)d_ws;
  unsigned short* xb  = (unsigned short*)(ws);               // 8 MB (cvt->qkv)
  unsigned short* Ab  = (unsigned short*)(ws);               // 8 MB (attn->out), overlays xb
  unsigned short* Wqb = (unsigned short*)(ws + 8388608);     // 2 MB
  unsigned short* Wkb = (unsigned short*)(ws + 10485760);    // 2 MB
  unsigned short* Wvb = (unsigned short*)(ws + 12582912);    // 2 MB
  unsigned short* Wob = (unsigned short*)(ws + 14680064);    // 2 MB
  unsigned short* Qb  = (unsigned short*)(ws + 16777216);    // 8 MB [B,H,S,D]
  unsigned short* Kbb = (unsigned short*)(ws + 25165824);    // 8 MB [B,H,S,D]
  unsigned short* Vtb = (unsigned short*)(ws + 33554432);    // 8 MB [B,H,D,S] (end 40 MB)

  cvt_all<<<dim3(8192), dim3(256), 0, stream>>>(x, Wq, Wk, Wv, Wo, xb, Wqb, Wkb, Wvb, Wob);
  qkv_gemm<<<dim3(32, 8, 3), dim3(256), 0, stream>>>(xb, Wqb, Wkb, Wvb, bq, bk, bv, Qb, Kbb, Vtb);
  attn_kernel<<<dim3(32, 16), dim3(256), 0, stream>>>(Qb, Kbb, Vtb, mask, Ab);
  out_gemm<<<dim3(32, 16), dim3(256), 0, stream>>>(Ab, Wob, bo, out);
}